// Round 1
// baseline (2272.015 us; speedup 1.0000x reference)
//
#include <hip/hip_runtime.h>
#include <math.h>

#define N_TOK 4096
#define S_LEN 2048
#define H_DIM 1024
#define E_EXP 8
#define CAPV  1536
#define NHEAD 8
#define HDHD  128

// ---------------------------------------------------------------- seasons
__global__ void season_k(float* seasons) {
    int s = blockIdx.x * 256 + threadIdx.x;
    if (s < S_LEN) {
        double a = (double)s * 2.0 * M_PI / 24.0;
        seasons[s] = (float)sin(a);
    }
}

// seas24[m][j] = (relu(season_m * Ws1 + bs1) @ Ws2 + bs2)[j], m = s % 24
__global__ void seas24_k(const float* __restrict__ seasons,
                         const float* __restrict__ Ws1, const float* __restrict__ bs1,
                         const float* __restrict__ Ws2, const float* __restrict__ bs2,
                         float* __restrict__ seas24) {
    __shared__ float hbuf[256];
    int m = blockIdx.x;          // 0..23
    float sv = seasons[m];
    int j = threadIdx.x;
    hbuf[j] = fmaxf(sv * Ws1[j] + bs1[j], 0.f);
    __syncthreads();
    float acc = bs2[j];
    for (int i = 0; i < 256; ++i) acc = fmaf(hbuf[i], Ws2[i * 256 + j], acc);
    seas24[m * 256 + j] = acc;
}

// ---------------------------------------------------------------- GEMM
// C[4096 x 1024] = epilogue(A[4096 x 1024] @ W[1024 x 1024])
// MODE 0: + bias
// MODE 1: relu(+ bias + t*rowT + season*rowS)          (enc layer 1)
// MODE 2: + bias + pos[s] + seas24[s%24][col&255]      (x assembly)
// MODE 3: relu(+ bias)                                 (router layer 1)
template <int MODE>
__global__ __launch_bounds__(256) void gemm128(
    const float* __restrict__ A, const float* __restrict__ W,
    const float* __restrict__ bias, float* __restrict__ C,
    const float* __restrict__ rowT, const float* __restrict__ rowS,
    const float* __restrict__ seasons, const float* __restrict__ pos,
    const float* __restrict__ seas24) {
    const int K = 1024, M = 1024;
    __shared__ float As[16][132];
    __shared__ float Bs[16][132];
    int tid = threadIdx.x;
    int tx = tid & 15, ty = tid >> 4;
    int m0 = blockIdx.y * 128;
    int n0 = blockIdx.x * 128;
    float acc[8][8] = {};
    for (int k0 = 0; k0 < K; k0 += 16) {
        __syncthreads();
        // stage A tile (128 x 16) transposed
#pragma unroll
        for (int i = 0; i < 2; ++i) {
            int f = tid * 2 + i;            // 0..511 float4s
            int row = f >> 2;
            int kq = f & 3;
            float4 v4 = *(const float4*)(A + (size_t)(m0 + row) * K + k0 + kq * 4);
            As[kq * 4 + 0][row] = v4.x;
            As[kq * 4 + 1][row] = v4.y;
            As[kq * 4 + 2][row] = v4.z;
            As[kq * 4 + 3][row] = v4.w;
        }
        // stage B tile (16 x 128)
#pragma unroll
        for (int i = 0; i < 2; ++i) {
            int f = tid * 2 + i;
            int kr = f >> 5;
            int c4 = f & 31;
            float4 v4 = *(const float4*)(W + (size_t)(k0 + kr) * M + n0 + c4 * 4);
            *(float4*)&Bs[kr][c4 * 4] = v4;
        }
        __syncthreads();
#pragma unroll
        for (int kk = 0; kk < 16; ++kk) {
            float a[8], b[8];
            *(float4*)&a[0] = *(const float4*)&As[kk][ty * 8];
            *(float4*)&a[4] = *(const float4*)&As[kk][ty * 8 + 4];
            *(float4*)&b[0] = *(const float4*)&Bs[kk][tx * 8];
            *(float4*)&b[4] = *(const float4*)&Bs[kk][tx * 8 + 4];
#pragma unroll
            for (int i2 = 0; i2 < 8; ++i2)
#pragma unroll
                for (int j2 = 0; j2 < 8; ++j2)
                    acc[i2][j2] = fmaf(a[i2], b[j2], acc[i2][j2]);
        }
    }
    // epilogue
#pragma unroll
    for (int i2 = 0; i2 < 8; ++i2) {
        int row = m0 + ty * 8 + i2;
        int s = row & (S_LEN - 1);
        float tval = 0.f, seval = 0.f;
        if (MODE == 1) { tval = (float)s; seval = seasons[s]; }
        const float* posrow = nullptr;
        const float* searow = nullptr;
        if (MODE == 2) {
            posrow = pos + (size_t)s * H_DIM;
            searow = seas24 + (size_t)(s % 24) * 256;
        }
#pragma unroll
        for (int j2 = 0; j2 < 8; ++j2) {
            int col = n0 + tx * 8 + j2;
            float v = acc[i2][j2] + bias[col];
            if (MODE == 1) v += tval * rowT[col] + seval * rowS[col];
            if (MODE == 2) v += posrow[col] + searow[col & 255];
            if (MODE == 1 || MODE == 3) v = fmaxf(v, 0.f);
            C[(size_t)row * M + col] = v;
        }
    }
}

// ---------------------------------------------------------------- attention
// flash-style f32. grid (S/64, B*NH), block 256.
// thread = (row r 0..63, d-group dg 0..3 of 32 dims)
__global__ __launch_bounds__(256) void attn_k(
    const float* __restrict__ q, const float* __restrict__ k,
    const float* __restrict__ v, float* __restrict__ ctx) {
    __shared__ float Ks[64][128];
    __shared__ float Vs[64][128];
    int bh = blockIdx.y;
    int b = bh >> 3, h = bh & 7;
    int q0 = blockIdx.x * 64;
    int tid = threadIdx.x;
    int dg = tid & 3, r = tid >> 2;
    size_t rowbase = ((size_t)(b * S_LEN + q0 + r)) * H_DIM + h * HDHD + dg * 32;
    float qreg[32];
#pragma unroll
    for (int i = 0; i < 8; ++i)
        *(float4*)&qreg[i * 4] = *(const float4*)(q + rowbase + i * 4);
    float O[32] = {};
    float mrun = -1e30f, lrun = 0.f;
    const float scale = 0.08838834764831845f;   // 1/sqrt(128)
    for (int kt = 0; kt < S_LEN; kt += 64) {
        __syncthreads();
#pragma unroll
        for (int i = 0; i < 8; ++i) {
            int f = tid + i * 256;
            int row = f >> 5, c4 = f & 31;
            size_t g = ((size_t)(b * S_LEN + kt + row)) * H_DIM + h * HDHD + c4 * 4;
            *(float4*)&Ks[row][c4 * 4] = *(const float4*)(k + g);
            *(float4*)&Vs[row][c4 * 4] = *(const float4*)(v + g);
        }
        __syncthreads();
        float sc[64];
        float tmax = -1e30f;
#pragma unroll
        for (int kr = 0; kr < 64; ++kr) {
            float p = 0.f;
#pragma unroll
            for (int d = 0; d < 32; d += 4) {
                const float4 kv = *(const float4*)&Ks[kr][dg * 32 + d];
                p = fmaf(qreg[d], kv.x, p);
                p = fmaf(qreg[d + 1], kv.y, p);
                p = fmaf(qreg[d + 2], kv.z, p);
                p = fmaf(qreg[d + 3], kv.w, p);
            }
            p += __shfl_xor(p, 1);
            p += __shfl_xor(p, 2);
            sc[kr] = p * scale;
            tmax = fmaxf(tmax, sc[kr]);
        }
        float mnew = fmaxf(mrun, tmax);
        float alpha = __expf(mrun - mnew);
        lrun *= alpha;
#pragma unroll
        for (int d = 0; d < 32; ++d) O[d] *= alpha;
#pragma unroll
        for (int kr = 0; kr < 64; ++kr) {
            float p = __expf(sc[kr] - mnew);
            lrun += p;
#pragma unroll
            for (int d = 0; d < 32; d += 4) {
                const float4 vv = *(const float4*)&Vs[kr][dg * 32 + d];
                O[d]     = fmaf(p, vv.x, O[d]);
                O[d + 1] = fmaf(p, vv.y, O[d + 1]);
                O[d + 2] = fmaf(p, vv.z, O[d + 2]);
                O[d + 3] = fmaf(p, vv.w, O[d + 3]);
            }
        }
        mrun = mnew;
    }
    float inv = 1.f / lrun;
#pragma unroll
    for (int i = 0; i < 8; ++i) {
        float4 o4 = make_float4(O[i * 4] * inv, O[i * 4 + 1] * inv,
                                O[i * 4 + 2] * inv, O[i * 4 + 3] * inv);
        *(float4*)(ctx + rowbase + i * 4) = o4;
    }
}

// ---------------------------------------------------------------- router logits
__global__ void logits_k(const float* __restrict__ h1, const float* __restrict__ Wr2,
                         const float* __restrict__ br2, float* __restrict__ logits) {
    int tid = threadIdx.x;
    int tok = blockIdx.x * 32 + (tid >> 3);
    int e = tid & 7;
    const float* hrow = h1 + (size_t)tok * 1024;
    float acc = br2[e];
    for (int i = 0; i < 1024; ++i) acc = fmaf(hrow[i], Wr2[i * 8 + e], acc);
    logits[(size_t)tok * 8 + e] = acc;
}

// ---------------------------------------------------------------- softmax + top2 + scatter
__global__ void topk_k(const float* __restrict__ logits, float* __restrict__ out) {
    int tok = blockIdx.x * 256 + threadIdx.x;
    if (tok >= N_TOK) return;
    float l[8], p[8];
    float mx = -1e30f;
#pragma unroll
    for (int e = 0; e < 8; ++e) { l[e] = logits[(size_t)tok * 8 + e]; mx = fmaxf(mx, l[e]); }
    float sum = 0.f;
#pragma unroll
    for (int e = 0; e < 8; ++e) { p[e] = __expf(l[e] - mx); sum += p[e]; }
    float inv = 1.f / sum;
#pragma unroll
    for (int e = 0; e < 8; ++e) p[e] *= inv;
    const size_t NEC = (size_t)N_TOK * E_EXP * CAPV;
    float* probs_out = out + 2 * NEC;
#pragma unroll
    for (int e = 0; e < 8; ++e) probs_out[(size_t)tok * 8 + e] = p[e];
    int i1 = 0;
#pragma unroll
    for (int e = 1; e < 8; ++e) if (p[e] > p[i1]) i1 = e;
    int i2 = -1;
#pragma unroll
    for (int e = 0; e < 8; ++e) {
        if (e == i1) continue;
        if (i2 < 0 || p[e] > p[i2]) i2 = e;
    }
    float v1 = p[i1], v2 = p[i2], tv = v1 + v2;
    size_t base = (size_t)tok * E_EXP * CAPV;
    out[base + (size_t)i1 * CAPV] = 1.f;
    out[base + (size_t)i2 * CAPV] = 1.f;
    out[NEC + base + (size_t)i1 * CAPV] = v1 / tv;
    out[NEC + base + (size_t)i2 * CAPV] = v2 / tv;
}

// ---------------------------------------------------------------- aux loss (deterministic)
__global__ void aux_k(const float* __restrict__ probs, float* __restrict__ out_aux) {
    __shared__ float part[256];
    int tid = threadIdx.x;
    int e = tid & 7, chunk = tid >> 3;  // 32 chunks x 128 tokens
    float s = 0.f;
    for (int t = chunk * 128; t < (chunk + 1) * 128; ++t)
        s += probs[(size_t)t * 8 + e];
    part[tid] = s;
    __syncthreads();
    if (tid < 8) {
        float tot = 0.f;
        for (int c = 0; c < 32; ++c) tot += part[c * 8 + e];
        part[tid] = tot / (float)N_TOK;
    }
    __syncthreads();
    if (tid == 0) {
        float aux = 0.f;
        for (int e2 = 0; e2 < 8; ++e2) {
            float pm = part[e2];
            aux += pm * logf(pm * 8.f + 1e-9f);
        }
        *out_aux = aux;
    }
}

// ---------------------------------------------------------------- launch
extern "C" void kernel_launch(void* const* d_in, const int* in_sizes, int n_in,
                              void* d_out, int out_size, void* d_ws, size_t ws_size,
                              hipStream_t stream) {
    const float* hid = (const float*)d_in[0];
    const float* pos = (const float*)d_in[1];
    const float* We1 = (const float*)d_in[2];
    const float* be1 = (const float*)d_in[3];
    const float* We2 = (const float*)d_in[4];
    const float* be2 = (const float*)d_in[5];
    const float* Ws1 = (const float*)d_in[6];
    const float* bs1 = (const float*)d_in[7];
    const float* Ws2 = (const float*)d_in[8];
    const float* bs2 = (const float*)d_in[9];
    const float* Wq  = (const float*)d_in[10]; const float* bq = (const float*)d_in[11];
    const float* Wk  = (const float*)d_in[12]; const float* bk = (const float*)d_in[13];
    const float* Wv  = (const float*)d_in[14]; const float* bv = (const float*)d_in[15];
    const float* Wo  = (const float*)d_in[16]; const float* bo = (const float*)d_in[17];
    const float* Wr1 = (const float*)d_in[18]; const float* br1 = (const float*)d_in[19];
    const float* Wr2 = (const float*)d_in[20]; const float* br2 = (const float*)d_in[21];

    float* out = (float*)d_out;
    float* ws = (float*)d_ws;
    const size_t M4 = (size_t)1 << 22;        // 4M floats = one (4096,1024) buffer
    float* xb    = ws;
    float* qb    = ws + 1 * M4;
    float* kb    = ws + 2 * M4;
    float* vb    = ws + 3 * M4;
    float* bufA  = ws + 4 * M4;               // A1 -> ctx -> h1
    float* bufB  = ws + 5 * M4;               // x2
    float* seas24  = ws + 6 * M4;             // 24*256
    float* seasons = seas24 + 8192;           // 2048
    float* logits  = seasons + 4096;          // 4096*8

    const size_t NEC = (size_t)N_TOK * E_EXP * CAPV;

    hipMemsetAsync(d_out, 0, (size_t)out_size * sizeof(float), stream);

    season_k<<<8, 256, 0, stream>>>(seasons);
    seas24_k<<<24, 256, 0, stream>>>(seasons, Ws1, bs1, Ws2, bs2, seas24);

    dim3 g(8, 32), blk(256);
    // enc layer 1: relu(hidden @ We1[:1024] + be1 + t*We1[1024] + season*We1[1025])
    gemm128<1><<<g, blk, 0, stream>>>(hid, We1, be1, bufA,
                                      We1 + (size_t)1024 * 1024, We1 + (size_t)1025 * 1024,
                                      seasons, nullptr, nullptr);
    // x = A1 @ We2 + be2 + pos + seas_full
    gemm128<2><<<g, blk, 0, stream>>>(bufA, We2, be2, xb,
                                      nullptr, nullptr, nullptr, pos, seas24);
    gemm128<0><<<g, blk, 0, stream>>>(xb, Wq, bq, qb, nullptr, nullptr, nullptr, nullptr, nullptr);
    gemm128<0><<<g, blk, 0, stream>>>(xb, Wk, bk, kb, nullptr, nullptr, nullptr, nullptr, nullptr);
    gemm128<0><<<g, blk, 0, stream>>>(xb, Wv, bv, vb, nullptr, nullptr, nullptr, nullptr, nullptr);

    attn_k<<<dim3(32, 16), 256, 0, stream>>>(qb, kb, vb, bufA);   // bufA = ctx

    gemm128<0><<<g, blk, 0, stream>>>(bufA, Wo, bo, bufB, nullptr, nullptr, nullptr, nullptr, nullptr);
    gemm128<3><<<g, blk, 0, stream>>>(bufB, Wr1, br1, bufA, nullptr, nullptr, nullptr, nullptr, nullptr);

    logits_k<<<128, 256, 0, stream>>>(bufA, Wr2, br2, logits);
    topk_k<<<16, 256, 0, stream>>>(logits, out);
    aux_k<<<1, 256, 0, stream>>>(out + 2 * NEC, out + 2 * NEC + (size_t)N_TOK * E_EXP);
}

// Round 2
// 2036.313 us; speedup vs baseline: 1.1157x; 1.1157x over previous
//
#include <hip/hip_runtime.h>
#include <math.h>

#define N_TOK 4096
#define S_LEN 2048
#define H_DIM 1024
#define E_EXP 8
#define CAPV  1536
#define NHEAD 8
#define HDHD  128

// ---------------------------------------------------------------- seasons
__global__ void season_k(float* seasons) {
    int s = blockIdx.x * 256 + threadIdx.x;
    if (s < S_LEN) {
        double a = (double)s * 2.0 * M_PI / 24.0;
        seasons[s] = (float)sin(a);
    }
}

// seas24[m][j] = (relu(season_m * Ws1 + bs1) @ Ws2 + bs2)[j], m = s % 24
__global__ void seas24_k(const float* __restrict__ seasons,
                         const float* __restrict__ Ws1, const float* __restrict__ bs1,
                         const float* __restrict__ Ws2, const float* __restrict__ bs2,
                         float* __restrict__ seas24) {
    __shared__ float hbuf[256];
    int m = blockIdx.x;          // 0..23
    float sv = seasons[m];
    int j = threadIdx.x;
    hbuf[j] = fmaxf(sv * Ws1[j] + bs1[j], 0.f);
    __syncthreads();
    float acc = bs2[j];
    for (int i = 0; i < 256; ++i) acc = fmaf(hbuf[i], Ws2[i * 256 + j], acc);
    seas24[m * 256 + j] = acc;
}

// ---------------------------------------------------------------- GEMM
// C[4096 x 1024] = epilogue(A[4096 x 1024] @ W[1024 x 1024])
template <int MODE>
__global__ __launch_bounds__(256) void gemm128(
    const float* __restrict__ A, const float* __restrict__ W,
    const float* __restrict__ bias, float* __restrict__ C,
    const float* __restrict__ rowT, const float* __restrict__ rowS,
    const float* __restrict__ seasons, const float* __restrict__ pos,
    const float* __restrict__ seas24) {
    const int K = 1024, M = 1024;
    __shared__ float As[16][132];
    __shared__ float Bs[16][132];
    int tid = threadIdx.x;
    int tx = tid & 15, ty = tid >> 4;
    int m0 = blockIdx.y * 128;
    int n0 = blockIdx.x * 128;
    float acc[8][8] = {};
    for (int k0 = 0; k0 < K; k0 += 16) {
        __syncthreads();
#pragma unroll
        for (int i = 0; i < 2; ++i) {
            int f = tid * 2 + i;
            int row = f >> 2;
            int kq = f & 3;
            float4 v4 = *(const float4*)(A + (size_t)(m0 + row) * K + k0 + kq * 4);
            As[kq * 4 + 0][row] = v4.x;
            As[kq * 4 + 1][row] = v4.y;
            As[kq * 4 + 2][row] = v4.z;
            As[kq * 4 + 3][row] = v4.w;
        }
#pragma unroll
        for (int i = 0; i < 2; ++i) {
            int f = tid * 2 + i;
            int kr = f >> 5;
            int c4 = f & 31;
            float4 v4 = *(const float4*)(W + (size_t)(k0 + kr) * M + n0 + c4 * 4);
            *(float4*)&Bs[kr][c4 * 4] = v4;
        }
        __syncthreads();
#pragma unroll
        for (int kk = 0; kk < 16; ++kk) {
            float a[8], b[8];
            *(float4*)&a[0] = *(const float4*)&As[kk][ty * 8];
            *(float4*)&a[4] = *(const float4*)&As[kk][ty * 8 + 4];
            *(float4*)&b[0] = *(const float4*)&Bs[kk][tx * 8];
            *(float4*)&b[4] = *(const float4*)&Bs[kk][tx * 8 + 4];
#pragma unroll
            for (int i2 = 0; i2 < 8; ++i2)
#pragma unroll
                for (int j2 = 0; j2 < 8; ++j2)
                    acc[i2][j2] = fmaf(a[i2], b[j2], acc[i2][j2]);
        }
    }
#pragma unroll
    for (int i2 = 0; i2 < 8; ++i2) {
        int row = m0 + ty * 8 + i2;
        int s = row & (S_LEN - 1);
        float tval = 0.f, seval = 0.f;
        if (MODE == 1) { tval = (float)s; seval = seasons[s]; }
        const float* posrow = nullptr;
        const float* searow = nullptr;
        if (MODE == 2) {
            posrow = pos + (size_t)s * H_DIM;
            searow = seas24 + (size_t)(s % 24) * 256;
        }
#pragma unroll
        for (int j2 = 0; j2 < 8; ++j2) {
            int col = n0 + tx * 8 + j2;
            float v = acc[i2][j2] + bias[col];
            if (MODE == 1) v += tval * rowT[col] + seval * rowS[col];
            if (MODE == 2) v += posrow[col] + searow[col & 255];
            if (MODE == 1 || MODE == 3) v = fmaxf(v, 0.f);
            C[(size_t)row * M + col] = v;
        }
    }
}

// ---------------------------------------------------------------- attention v2
// register-tiled f32 flash. grid (S/64, B*NH), block 256 = 16(qi) x 16(kj).
// Each thread: 4 q-rows (qi*4..+3) x {4 k-cols | 8 v-dims}.
// LDS: Qs,Ks d-major [128][68] XOR-swizzled; Vs [64][132]; Ps [64][68].
#define QS_OFF 0
#define KS_OFF (128 * 68)
#define VS_OFF (2 * 128 * 68)
#define PS_OFF (2 * 128 * 68 + 64 * 132)
#define ATTN_LDS_BYTES ((2 * 128 * 68 + 64 * 132 + 64 * 68) * 4)

__global__ __launch_bounds__(256) void attn_k(
    const float* __restrict__ q, const float* __restrict__ k,
    const float* __restrict__ v, float* __restrict__ ctx) {
    extern __shared__ float smem[];
    float* Qs = smem + QS_OFF;
    float* Ks = smem + KS_OFF;
    float* Vs = smem + VS_OFF;
    float* Ps = smem + PS_OFF;

    int bh = blockIdx.y;
    int b = bh >> 3, h = bh & 7;
    int q0 = blockIdx.x * 64;
    int tid = threadIdx.x;
    int qi = tid >> 4;          // 0..15
    int kj = tid & 15;          // 0..15
    const float scale = 0.08838834764831845f;   // 1/sqrt(128)

    // ---- stage Q tile (64 x 128) d-major, swizzled, scale folded in
#pragma unroll
    for (int i = 0; i < 8; ++i) {
        int f = tid + i * 256;
        int row = f >> 5, c4 = f & 31;
        float4 v4 = *(const float4*)(q + ((size_t)(b * S_LEN + q0 + row)) * H_DIM + h * HDHD + c4 * 4);
        int s4 = ((c4 >> 1) & 7) * 4;
        float vals[4] = {v4.x * scale, v4.y * scale, v4.z * scale, v4.w * scale};
#pragma unroll
        for (int cc = 0; cc < 4; ++cc)
            Qs[(c4 * 4 + cc) * 68 + (row ^ s4)] = vals[cc];
    }

    float O[4][8] = {};
    float m[4] = {-1e30f, -1e30f, -1e30f, -1e30f};
    float l[4] = {};

    for (int kt = 0; kt < S_LEN; kt += 64) {
        __syncthreads();    // prev PV done with Vs/Ps before restage
        // ---- stage K (d-major, swizzled) and V (row-major)
#pragma unroll
        for (int i = 0; i < 8; ++i) {
            int f = tid + i * 256;
            int row = f >> 5, c4 = f & 31;
            size_t g = ((size_t)(b * S_LEN + kt + row)) * H_DIM + h * HDHD + c4 * 4;
            float4 kv = *(const float4*)(k + g);
            float4 vv = *(const float4*)(v + g);
            int s4 = ((c4 >> 1) & 7) * 4;
            Ks[(c4 * 4 + 0) * 68 + (row ^ s4)] = kv.x;
            Ks[(c4 * 4 + 1) * 68 + (row ^ s4)] = kv.y;
            Ks[(c4 * 4 + 2) * 68 + (row ^ s4)] = kv.z;
            Ks[(c4 * 4 + 3) * 68 + (row ^ s4)] = kv.w;
            *(float4*)&Vs[row * 132 + c4 * 4] = vv;
        }
        __syncthreads();

        // ---- QK^T: 4x4 outer product over d
        float acc[4][4] = {};
#pragma unroll 8
        for (int d = 0; d < 128; ++d) {
            int s4 = ((d >> 3) & 7) * 4;
            float4 a  = *(const float4*)&Qs[d * 68 + ((qi * 4) ^ s4)];
            float4 bb = *(const float4*)&Ks[d * 68 + ((kj * 4) ^ s4)];
            float av[4] = {a.x, a.y, a.z, a.w};
            float bv[4] = {bb.x, bb.y, bb.z, bb.w};
#pragma unroll
            for (int qq = 0; qq < 4; ++qq)
#pragma unroll
                for (int kk = 0; kk < 4; ++kk)
                    acc[qq][kk] = fmaf(av[qq], bv[kk], acc[qq][kk]);
        }

        // ---- online softmax (row stats across the 16 kj lanes)
        float p[4][4];
#pragma unroll
        for (int qq = 0; qq < 4; ++qq) {
            float mt = fmaxf(fmaxf(acc[qq][0], acc[qq][1]), fmaxf(acc[qq][2], acc[qq][3]));
            mt = fmaxf(mt, __shfl_xor(mt, 1));
            mt = fmaxf(mt, __shfl_xor(mt, 2));
            mt = fmaxf(mt, __shfl_xor(mt, 4));
            mt = fmaxf(mt, __shfl_xor(mt, 8));
            float mnew = fmaxf(m[qq], mt);
            float alpha = __expf(m[qq] - mnew);
            float lt = 0.f;
#pragma unroll
            for (int kk = 0; kk < 4; ++kk) {
                p[qq][kk] = __expf(acc[qq][kk] - mnew);
                lt += p[qq][kk];
            }
            lt += __shfl_xor(lt, 1);
            lt += __shfl_xor(lt, 2);
            lt += __shfl_xor(lt, 4);
            lt += __shfl_xor(lt, 8);
            l[qq] = l[qq] * alpha + lt;
            m[qq] = mnew;
#pragma unroll
            for (int c = 0; c < 8; ++c) O[qq][c] *= alpha;
        }

        // ---- P -> LDS (k-major rows, q columns)
#pragma unroll
        for (int kk = 0; kk < 4; ++kk) {
            float4 w = make_float4(p[0][kk], p[1][kk], p[2][kk], p[3][kk]);
            *(float4*)&Ps[(kj * 4 + kk) * 68 + qi * 4] = w;
        }
        __syncthreads();

        // ---- PV: 4x8 outer product over k-rows
#pragma unroll 4
        for (int kr = 0; kr < 64; ++kr) {
            float4 a  = *(const float4*)&Ps[kr * 68 + qi * 4];
            float4 b0 = *(const float4*)&Vs[kr * 132 + kj * 4];
            float4 b1 = *(const float4*)&Vs[kr * 132 + 64 + kj * 4];
            float av[4] = {a.x, a.y, a.z, a.w};
            float b0v[4] = {b0.x, b0.y, b0.z, b0.w};
            float b1v[4] = {b1.x, b1.y, b1.z, b1.w};
#pragma unroll
            for (int qq = 0; qq < 4; ++qq) {
#pragma unroll
                for (int c = 0; c < 4; ++c) {
                    O[qq][c]     = fmaf(av[qq], b0v[c], O[qq][c]);
                    O[qq][c + 4] = fmaf(av[qq], b1v[c], O[qq][c + 4]);
                }
            }
        }
    }

    // ---- epilogue
#pragma unroll
    for (int qq = 0; qq < 4; ++qq) {
        float inv = 1.f / l[qq];
        size_t g = ((size_t)(b * S_LEN + q0 + qi * 4 + qq)) * H_DIM + h * HDHD;
        float4 o0 = make_float4(O[qq][0] * inv, O[qq][1] * inv, O[qq][2] * inv, O[qq][3] * inv);
        float4 o1 = make_float4(O[qq][4] * inv, O[qq][5] * inv, O[qq][6] * inv, O[qq][7] * inv);
        *(float4*)(ctx + g + kj * 4) = o0;
        *(float4*)(ctx + g + 64 + kj * 4) = o1;
    }
}

// ---------------------------------------------------------------- router logits
__global__ void logits_k(const float* __restrict__ h1, const float* __restrict__ Wr2,
                         const float* __restrict__ br2, float* __restrict__ logits) {
    int tid = threadIdx.x;
    int tok = blockIdx.x * 32 + (tid >> 3);
    int e = tid & 7;
    const float* hrow = h1 + (size_t)tok * 1024;
    float acc = br2[e];
    for (int i = 0; i < 1024; ++i) acc = fmaf(hrow[i], Wr2[i * 8 + e], acc);
    logits[(size_t)tok * 8 + e] = acc;
}

// ---------------------------------------------------------------- softmax + top2 + scatter
__global__ void topk_k(const float* __restrict__ logits, float* __restrict__ out) {
    int tok = blockIdx.x * 256 + threadIdx.x;
    if (tok >= N_TOK) return;
    float l[8], p[8];
    float mx = -1e30f;
#pragma unroll
    for (int e = 0; e < 8; ++e) { l[e] = logits[(size_t)tok * 8 + e]; mx = fmaxf(mx, l[e]); }
    float sum = 0.f;
#pragma unroll
    for (int e = 0; e < 8; ++e) { p[e] = __expf(l[e] - mx); sum += p[e]; }
    float inv = 1.f / sum;
#pragma unroll
    for (int e = 0; e < 8; ++e) p[e] *= inv;
    const size_t NEC = (size_t)N_TOK * E_EXP * CAPV;
    float* probs_out = out + 2 * NEC;
#pragma unroll
    for (int e = 0; e < 8; ++e) probs_out[(size_t)tok * 8 + e] = p[e];
    int i1 = 0;
#pragma unroll
    for (int e = 1; e < 8; ++e) if (p[e] > p[i1]) i1 = e;
    int i2 = -1;
#pragma unroll
    for (int e = 0; e < 8; ++e) {
        if (e == i1) continue;
        if (i2 < 0 || p[e] > p[i2]) i2 = e;
    }
    float v1 = p[i1], v2 = p[i2], tv = v1 + v2;
    size_t base = (size_t)tok * E_EXP * CAPV;
    out[base + (size_t)i1 * CAPV] = 1.f;
    out[base + (size_t)i2 * CAPV] = 1.f;
    out[NEC + base + (size_t)i1 * CAPV] = v1 / tv;
    out[NEC + base + (size_t)i2 * CAPV] = v2 / tv;
}

// ---------------------------------------------------------------- aux loss (deterministic)
__global__ void aux_k(const float* __restrict__ probs, float* __restrict__ out_aux) {
    __shared__ float part[256];
    int tid = threadIdx.x;
    int e = tid & 7, chunk = tid >> 3;
    float s = 0.f;
    for (int t = chunk * 128; t < (chunk + 1) * 128; ++t)
        s += probs[(size_t)t * 8 + e];
    part[tid] = s;
    __syncthreads();
    if (tid < 8) {
        float tot = 0.f;
        for (int c = 0; c < 32; ++c) tot += part[c * 8 + e];
        part[tid] = tot / (float)N_TOK;
    }
    __syncthreads();
    if (tid == 0) {
        float aux = 0.f;
        for (int e2 = 0; e2 < 8; ++e2) {
            float pm = part[e2];
            aux += pm * logf(pm * 8.f + 1e-9f);
        }
        *out_aux = aux;
    }
}

// ---------------------------------------------------------------- launch
extern "C" void kernel_launch(void* const* d_in, const int* in_sizes, int n_in,
                              void* d_out, int out_size, void* d_ws, size_t ws_size,
                              hipStream_t stream) {
    const float* hid = (const float*)d_in[0];
    const float* pos = (const float*)d_in[1];
    const float* We1 = (const float*)d_in[2];
    const float* be1 = (const float*)d_in[3];
    const float* We2 = (const float*)d_in[4];
    const float* be2 = (const float*)d_in[5];
    const float* Ws1 = (const float*)d_in[6];
    const float* bs1 = (const float*)d_in[7];
    const float* Ws2 = (const float*)d_in[8];
    const float* bs2 = (const float*)d_in[9];
    const float* Wq  = (const float*)d_in[10]; const float* bq = (const float*)d_in[11];
    const float* Wk  = (const float*)d_in[12]; const float* bk = (const float*)d_in[13];
    const float* Wv  = (const float*)d_in[14]; const float* bv = (const float*)d_in[15];
    const float* Wo  = (const float*)d_in[16]; const float* bo = (const float*)d_in[17];
    const float* Wr1 = (const float*)d_in[18]; const float* br1 = (const float*)d_in[19];
    const float* Wr2 = (const float*)d_in[20]; const float* br2 = (const float*)d_in[21];

    float* out = (float*)d_out;
    float* ws = (float*)d_ws;
    const size_t M4 = (size_t)1 << 22;
    float* xb    = ws;
    float* qb    = ws + 1 * M4;
    float* kb    = ws + 2 * M4;
    float* vb    = ws + 3 * M4;
    float* bufA  = ws + 4 * M4;
    float* bufB  = ws + 5 * M4;
    float* seas24  = ws + 6 * M4;
    float* seasons = seas24 + 8192;
    float* logits  = seasons + 4096;

    const size_t NEC = (size_t)N_TOK * E_EXP * CAPV;

    static bool attr_set = false;
    if (!attr_set) {
        hipFuncSetAttribute((const void*)attn_k,
                            hipFuncAttributeMaxDynamicSharedMemorySize,
                            ATTN_LDS_BYTES);
        attr_set = true;
    }

    hipMemsetAsync(d_out, 0, (size_t)out_size * sizeof(float), stream);

    season_k<<<8, 256, 0, stream>>>(seasons);
    seas24_k<<<24, 256, 0, stream>>>(seasons, Ws1, bs1, Ws2, bs2, seas24);

    dim3 g(8, 32), blk(256);
    gemm128<1><<<g, blk, 0, stream>>>(hid, We1, be1, bufA,
                                      We1 + (size_t)1024 * 1024, We1 + (size_t)1025 * 1024,
                                      seasons, nullptr, nullptr);
    gemm128<2><<<g, blk, 0, stream>>>(bufA, We2, be2, xb,
                                      nullptr, nullptr, nullptr, pos, seas24);
    gemm128<0><<<g, blk, 0, stream>>>(xb, Wq, bq, qb, nullptr, nullptr, nullptr, nullptr, nullptr);
    gemm128<0><<<g, blk, 0, stream>>>(xb, Wk, bk, kb, nullptr, nullptr, nullptr, nullptr, nullptr);
    gemm128<0><<<g, blk, 0, stream>>>(xb, Wv, bv, vb, nullptr, nullptr, nullptr, nullptr, nullptr);

    attn_k<<<dim3(32, 16), 256, ATTN_LDS_BYTES, stream>>>(qb, kb, vb, bufA);

    gemm128<0><<<g, blk, 0, stream>>>(bufA, Wo, bo, bufB, nullptr, nullptr, nullptr, nullptr, nullptr);
    gemm128<3><<<g, blk, 0, stream>>>(bufB, Wr1, br1, bufA, nullptr, nullptr, nullptr, nullptr, nullptr);

    logits_k<<<128, 256, 0, stream>>>(bufA, Wr2, br2, logits);
    topk_k<<<16, 256, 0, stream>>>(logits, out);
    aux_k<<<1, 256, 0, stream>>>(out + 2 * NEC, out + 2 * NEC + (size_t)N_TOK * E_EXP);
}

// Round 3
// 1084.139 us; speedup vs baseline: 2.0957x; 1.8783x over previous
//
#include <hip/hip_runtime.h>
#include <hip/hip_fp16.h>
#include <math.h>

#define N_TOK 4096
#define S_LEN 2048
#define H_DIM 1024
#define E_EXP 8
#define CAPV  1536
#define NHEAD 8
#define HDHD  128

typedef __attribute__((ext_vector_type(8))) _Float16 v8h;
typedef __attribute__((ext_vector_type(4))) float v4f;

__device__ __forceinline__ void splitf16(float v, unsigned short& h, unsigned short& l) {
    __half hh = __float2half(v);
    h = __half_as_ushort(hh);
    l = __half_as_ushort(__float2half(v - __half2float(hh)));
}

__device__ __forceinline__ void gld_lds16(const void* g, void* l) {
    __builtin_amdgcn_global_load_lds(
        (const __attribute__((address_space(1))) unsigned int*)g,
        (__attribute__((address_space(3))) unsigned int*)l,
        16, 0, 0);
}

// ---------------------------------------------------------------- seasons
__global__ void season_k(float* seasons) {
    int s = blockIdx.x * 256 + threadIdx.x;
    if (s < S_LEN) {
        double a = (double)s * 2.0 * M_PI / 24.0;
        seasons[s] = (float)sin(a);
    }
}

__global__ void seas24_k(const float* __restrict__ seasons,
                         const float* __restrict__ Ws1, const float* __restrict__ bs1,
                         const float* __restrict__ Ws2, const float* __restrict__ bs2,
                         float* __restrict__ seas24) {
    __shared__ float hbuf[256];
    int m = blockIdx.x;
    float sv = seasons[m];
    int j = threadIdx.x;
    hbuf[j] = fmaxf(sv * Ws1[j] + bs1[j], 0.f);
    __syncthreads();
    float acc = bs2[j];
    for (int i = 0; i < 256; ++i) acc = fmaf(hbuf[i], Ws2[i * 256 + j], acc);
    seas24[m * 256 + j] = acc;
}

// ---------------------------------------------------------------- f32 -> f16 hi/lo split
__global__ void convert_split_k(const float* __restrict__ in,
                                unsigned short* __restrict__ hi,
                                unsigned short* __restrict__ lo, int n4) {
    int i = blockIdx.x * 256 + threadIdx.x;
    if (i >= n4) return;
    float4 v = ((const float4*)in)[i];
    ushort4 h, l;
    splitf16(v.x, h.x, l.x);
    splitf16(v.y, h.y, l.y);
    splitf16(v.z, h.z, l.z);
    splitf16(v.w, h.w, l.w);
    ((ushort4*)hi)[i] = h;
    ((ushort4*)lo)[i] = l;
}

// ---------------------------------------------------------------- W[1024][1024] -> W^T hi/lo f16
__global__ __launch_bounds__(256) void wconv_t_k(const float* __restrict__ W,
                                                 unsigned short* __restrict__ Thi,
                                                 unsigned short* __restrict__ Tlo) {
    __shared__ unsigned short Hs[64][65];
    __shared__ unsigned short Ls[64][65];
    int k0 = blockIdx.y * 64, n0 = blockIdx.x * 64;
    int tid = threadIdx.x;
#pragma unroll
    for (int i = 0; i < 4; ++i) {
        int idx = tid + i * 256;
        int kk = idx >> 4, n4 = idx & 15;
        float4 v = *(const float4*)(W + (size_t)(k0 + kk) * 1024 + n0 + n4 * 4);
        unsigned short h, l;
        splitf16(v.x, h, l); Hs[n4 * 4 + 0][kk] = h; Ls[n4 * 4 + 0][kk] = l;
        splitf16(v.y, h, l); Hs[n4 * 4 + 1][kk] = h; Ls[n4 * 4 + 1][kk] = l;
        splitf16(v.z, h, l); Hs[n4 * 4 + 2][kk] = h; Ls[n4 * 4 + 2][kk] = l;
        splitf16(v.w, h, l); Hs[n4 * 4 + 3][kk] = h; Ls[n4 * 4 + 3][kk] = l;
    }
    __syncthreads();
#pragma unroll
    for (int i = 0; i < 4; ++i) {
        int idx = tid + i * 256;
        int n = idx >> 4, k4 = idx & 15;
        ushort4 h = make_ushort4(Hs[n][k4 * 4], Hs[n][k4 * 4 + 1], Hs[n][k4 * 4 + 2], Hs[n][k4 * 4 + 3]);
        ushort4 l = make_ushort4(Ls[n][k4 * 4], Ls[n][k4 * 4 + 1], Ls[n][k4 * 4 + 2], Ls[n][k4 * 4 + 3]);
        *(ushort4*)(Thi + (size_t)(n0 + n) * 1024 + k0 + k4 * 4) = h;
        *(ushort4*)(Tlo + (size_t)(n0 + n) * 1024 + k0 + k4 * 4) = l;
    }
}

// ---------------------------------------------------------------- split-f16 MFMA GEMM
// C[4096 x 1024] = A @ W, A as (Ahi+Alo) [4096][1024] f16, W^T as (Whi+Wlo) [n][k] f16.
// 3 phases: hi*hi + lo*hi + hi*lo. Tile 128(M) x 64(N), BK=32, 4 waves (2x2).
// MODE 0: +bias | 1: relu(+bias+t*rowT+s*rowS) | 2: +bias+pos+seas24 | 3: relu(+bias)
// EMITF: write f32 C; EMITS: write f16 split Chi/Clo.
template <int MODE, int EMITF, int EMITS>
__global__ __launch_bounds__(256, 2) void gemm_split(
    const unsigned short* __restrict__ Ahi, const unsigned short* __restrict__ Alo,
    const unsigned short* __restrict__ WThi, const unsigned short* __restrict__ WTlo,
    const float* __restrict__ bias, float* __restrict__ Cf,
    unsigned short* __restrict__ Chi, unsigned short* __restrict__ Clo,
    const float* __restrict__ rowT, const float* __restrict__ rowS,
    const float* __restrict__ seasons, const float* __restrict__ pos,
    const float* __restrict__ seas24) {
    __shared__ unsigned short As[128 * 32];
    __shared__ unsigned short Bs[64 * 32];
    int tid = threadIdx.x;
    int lane = tid & 63, w = tid >> 6;
    int l15 = lane & 15, l16 = lane >> 4;
    int wm = (w >> 1) * 64, wn = (w & 1) * 32;
    int m0 = blockIdx.y * 128, n0 = blockIdx.x * 64;

    // staging addresses (pre-swizzled global source, linear LDS dest)
    int ac0 = w * 128 + lane;          // A chunk 0 (of 512)
    int ac1 = ac0 + 64;                // A chunk 1
    int bc  = w * 64 + lane;           // B chunk (of 256)
    int ar0 = ac0 >> 2, ar1 = ac1 >> 2, bn = bc >> 2;
    size_t a_src0 = (size_t)(m0 + ar0) * 1024 + (((ac0 & 3) ^ (ar0 & 3)) * 8);
    size_t a_src1 = (size_t)(m0 + ar1) * 1024 + (((ac1 & 3) ^ (ar1 & 3)) * 8);
    size_t b_src  = (size_t)(n0 + bn) * 1024 + (((bc & 3) ^ (bn & 3)) * 8);
    unsigned short* a_lds0 = &As[ac0 * 8];
    unsigned short* a_lds1 = &As[ac1 * 8];
    unsigned short* b_lds  = &Bs[bc * 8];

    // fragment read offsets (swizzled)
    int a_off[4], b_off[2];
#pragma unroll
    for (int mi = 0; mi < 4; ++mi) {
        int row = wm + mi * 16 + l15;
        a_off[mi] = row * 32 + ((l16 ^ (row & 3)) * 8);
    }
#pragma unroll
    for (int ni = 0; ni < 2; ++ni) {
        int n = wn + ni * 16 + l15;
        b_off[ni] = n * 32 + ((l16 ^ (n & 3)) * 8);
    }

    v4f acc[4][2] = {};
    const unsigned short* aph[3] = {Ahi, Alo, Ahi};
    const unsigned short* wph[3] = {WThi, WThi, WTlo};

    for (int ph = 0; ph < 3; ++ph) {
        const unsigned short* __restrict__ pa = aph[ph];
        const unsigned short* __restrict__ pw = wph[ph];
        for (int k0 = 0; k0 < 1024; k0 += 32) {
            __syncthreads();
            gld_lds16(pa + a_src0 + k0, a_lds0);
            gld_lds16(pa + a_src1 + k0, a_lds1);
            gld_lds16(pw + b_src + k0, b_lds);
            __syncthreads();
            v8h a0 = *(const v8h*)&As[a_off[0]];
            v8h a1 = *(const v8h*)&As[a_off[1]];
            v8h a2 = *(const v8h*)&As[a_off[2]];
            v8h a3 = *(const v8h*)&As[a_off[3]];
            v8h b0 = *(const v8h*)&Bs[b_off[0]];
            v8h b1 = *(const v8h*)&Bs[b_off[1]];
            acc[0][0] = __builtin_amdgcn_mfma_f32_16x16x32_f16(a0, b0, acc[0][0], 0, 0, 0);
            acc[0][1] = __builtin_amdgcn_mfma_f32_16x16x32_f16(a0, b1, acc[0][1], 0, 0, 0);
            acc[1][0] = __builtin_amdgcn_mfma_f32_16x16x32_f16(a1, b0, acc[1][0], 0, 0, 0);
            acc[1][1] = __builtin_amdgcn_mfma_f32_16x16x32_f16(a1, b1, acc[1][1], 0, 0, 0);
            acc[2][0] = __builtin_amdgcn_mfma_f32_16x16x32_f16(a2, b0, acc[2][0], 0, 0, 0);
            acc[2][1] = __builtin_amdgcn_mfma_f32_16x16x32_f16(a2, b1, acc[2][1], 0, 0, 0);
            acc[3][0] = __builtin_amdgcn_mfma_f32_16x16x32_f16(a3, b0, acc[3][0], 0, 0, 0);
            acc[3][1] = __builtin_amdgcn_mfma_f32_16x16x32_f16(a3, b1, acc[3][1], 0, 0, 0);
        }
    }

    // epilogue
#pragma unroll
    for (int mi = 0; mi < 4; ++mi) {
#pragma unroll
        for (int r = 0; r < 4; ++r) {
            int row = m0 + wm + mi * 16 + l16 * 4 + r;
            int s = row & (S_LEN - 1);
            float tval = 0.f, seval = 0.f;
            if (MODE == 1) { tval = (float)s; seval = seasons[s]; }
#pragma unroll
            for (int ni = 0; ni < 2; ++ni) {
                int col = n0 + wn + ni * 16 + l15;
                float v = acc[mi][ni][r] + bias[col];
                if (MODE == 1) v += tval * rowT[col] + seval * rowS[col];
                if (MODE == 2) v += pos[(size_t)s * 1024 + col] + seas24[(s % 24) * 256 + (col & 255)];
                if (MODE == 1 || MODE == 3) v = fmaxf(v, 0.f);
                size_t o = (size_t)row * 1024 + col;
                if (EMITF) Cf[o] = v;
                if (EMITS) {
                    unsigned short hu, lu;
                    splitf16(v, hu, lu);
                    Chi[o] = hu; Clo[o] = lu;
                }
            }
        }
    }
}

// ---------------------------------------------------------------- attention (f32, KT=32)
// grid (S/64, B*NH), block 256 = 16(qi) x 16(kj). thread: 4 q-rows x {2 k-cols | 8 v-dims}
#define KT 32
#define QS_OFF 0
#define KS_OFF (128 * 68)
#define VS_OFF (128 * 68 + 128 * 36)
#define PS_OFF (128 * 68 + 128 * 36 + KT * 132)
#define ATTN_LDS_BYTES ((128 * 68 + 128 * 36 + KT * 132 + KT * 68) * 4)

__global__ __launch_bounds__(256, 2) void attn_k(
    const float* __restrict__ q, const float* __restrict__ k,
    const float* __restrict__ v,
    unsigned short* __restrict__ ctx_hi, unsigned short* __restrict__ ctx_lo) {
    extern __shared__ float smem[];
    float* Qs = smem + QS_OFF;
    float* Ks = smem + KS_OFF;
    float* Vs = smem + VS_OFF;
    float* Ps = smem + PS_OFF;

    int bh = blockIdx.y;
    int b = bh >> 3, h = bh & 7;
    int q0 = blockIdx.x * 64;
    int tid = threadIdx.x;
    int qi = tid >> 4;
    int kj = tid & 15;
    const float scale = 0.08838834764831845f;

    // stage Q (64 x 128) d-major swizzled, scale folded
#pragma unroll
    for (int i = 0; i < 8; ++i) {
        int f = tid + i * 256;
        int row = f >> 5, c4 = f & 31;
        float4 v4 = *(const float4*)(q + ((size_t)(b * S_LEN + q0 + row)) * H_DIM + h * HDHD + c4 * 4);
        int s4 = ((c4 >> 1) & 7) * 4;
        Qs[(c4 * 4 + 0) * 68 + (row ^ s4)] = v4.x * scale;
        Qs[(c4 * 4 + 1) * 68 + (row ^ s4)] = v4.y * scale;
        Qs[(c4 * 4 + 2) * 68 + (row ^ s4)] = v4.z * scale;
        Qs[(c4 * 4 + 3) * 68 + (row ^ s4)] = v4.w * scale;
    }

    float O[4][8] = {};
    float m[4] = {-1e30f, -1e30f, -1e30f, -1e30f};
    float l[4] = {};

    for (int kt = 0; kt < S_LEN; kt += KT) {
        __syncthreads();
#pragma unroll
        for (int i = 0; i < 4; ++i) {
            int f = tid + i * 256;
            int row = f >> 5, c4 = f & 31;
            size_t g = ((size_t)(b * S_LEN + kt + row)) * H_DIM + h * HDHD + c4 * 4;
            float4 kv = *(const float4*)(k + g);
            float4 vv = *(const float4*)(v + g);
            int s4 = ((c4 >> 1) & 7) * 4;
            Ks[(c4 * 4 + 0) * 36 + (row ^ s4)] = kv.x;
            Ks[(c4 * 4 + 1) * 36 + (row ^ s4)] = kv.y;
            Ks[(c4 * 4 + 2) * 36 + (row ^ s4)] = kv.z;
            Ks[(c4 * 4 + 3) * 36 + (row ^ s4)] = kv.w;
            *(float4*)&Vs[row * 132 + c4 * 4] = vv;
        }
        __syncthreads();

        // QK^T 4x2
        float acc[4][2] = {};
#pragma unroll 8
        for (int d = 0; d < 128; ++d) {
            int s4 = ((d >> 3) & 7) * 4;
            float4 a = *(const float4*)&Qs[d * 68 + ((qi * 4) ^ s4)];
            float2 bb = *(const float2*)&Ks[d * 36 + ((kj * 2) ^ s4)];
            float av[4] = {a.x, a.y, a.z, a.w};
#pragma unroll
            for (int qq = 0; qq < 4; ++qq) {
                acc[qq][0] = fmaf(av[qq], bb.x, acc[qq][0]);
                acc[qq][1] = fmaf(av[qq], bb.y, acc[qq][1]);
            }
        }

        // online softmax
        float p[4][2];
#pragma unroll
        for (int qq = 0; qq < 4; ++qq) {
            float mt = fmaxf(acc[qq][0], acc[qq][1]);
            mt = fmaxf(mt, __shfl_xor(mt, 1));
            mt = fmaxf(mt, __shfl_xor(mt, 2));
            mt = fmaxf(mt, __shfl_xor(mt, 4));
            mt = fmaxf(mt, __shfl_xor(mt, 8));
            float mnew = fmaxf(m[qq], mt);
            float alpha = __expf(m[qq] - mnew);
            p[qq][0] = __expf(acc[qq][0] - mnew);
            p[qq][1] = __expf(acc[qq][1] - mnew);
            float lt = p[qq][0] + p[qq][1];
            lt += __shfl_xor(lt, 1);
            lt += __shfl_xor(lt, 2);
            lt += __shfl_xor(lt, 4);
            lt += __shfl_xor(lt, 8);
            l[qq] = l[qq] * alpha + lt;
            m[qq] = mnew;
#pragma unroll
            for (int c = 0; c < 8; ++c) O[qq][c] *= alpha;
        }

        // P -> LDS
#pragma unroll
        for (int kk = 0; kk < 2; ++kk) {
            float4 wv = make_float4(p[0][kk], p[1][kk], p[2][kk], p[3][kk]);
            *(float4*)&Ps[(kj * 2 + kk) * 68 + qi * 4] = wv;
        }
        __syncthreads();

        // PV
#pragma unroll 4
        for (int kr = 0; kr < KT; ++kr) {
            float4 a  = *(const float4*)&Ps[kr * 68 + qi * 4];
            float4 b0 = *(const float4*)&Vs[kr * 132 + kj * 4];
            float4 b1 = *(const float4*)&Vs[kr * 132 + 64 + kj * 4];
            float av[4] = {a.x, a.y, a.z, a.w};
            float b0v[4] = {b0.x, b0.y, b0.z, b0.w};
            float b1v[4] = {b1.x, b1.y, b1.z, b1.w};
#pragma unroll
            for (int qq = 0; qq < 4; ++qq) {
#pragma unroll
                for (int c = 0; c < 4; ++c) {
                    O[qq][c]     = fmaf(av[qq], b0v[c], O[qq][c]);
                    O[qq][c + 4] = fmaf(av[qq], b1v[c], O[qq][c + 4]);
                }
            }
        }
    }

    // epilogue: emit ctx as f16 split
#pragma unroll
    for (int qq = 0; qq < 4; ++qq) {
        float inv = 1.f / l[qq];
        size_t g = ((size_t)(b * S_LEN + q0 + qi * 4 + qq)) * H_DIM + h * HDHD;
        ushort4 h0, h1, l0, l1;
        splitf16(O[qq][0] * inv, h0.x, l0.x);
        splitf16(O[qq][1] * inv, h0.y, l0.y);
        splitf16(O[qq][2] * inv, h0.z, l0.z);
        splitf16(O[qq][3] * inv, h0.w, l0.w);
        splitf16(O[qq][4] * inv, h1.x, l1.x);
        splitf16(O[qq][5] * inv, h1.y, l1.y);
        splitf16(O[qq][6] * inv, h1.z, l1.z);
        splitf16(O[qq][7] * inv, h1.w, l1.w);
        *(ushort4*)(ctx_hi + g + kj * 4) = h0;
        *(ushort4*)(ctx_hi + g + 64 + kj * 4) = h1;
        *(ushort4*)(ctx_lo + g + kj * 4) = l0;
        *(ushort4*)(ctx_lo + g + 64 + kj * 4) = l1;
    }
}

// ---------------------------------------------------------------- router logits
__global__ void logits_k(const float* __restrict__ h1, const float* __restrict__ Wr2,
                         const float* __restrict__ br2, float* __restrict__ logits) {
    int tid = threadIdx.x;
    int tok = blockIdx.x * 32 + (tid >> 3);
    int e = tid & 7;
    const float* hrow = h1 + (size_t)tok * 1024;
    float acc = br2[e];
    for (int i = 0; i < 1024; ++i) acc = fmaf(hrow[i], Wr2[i * 8 + e], acc);
    logits[(size_t)tok * 8 + e] = acc;
}

// ---------------------------------------------------------------- softmax + top2 + scatter
__global__ void topk_k(const float* __restrict__ logits, float* __restrict__ out) {
    int tok = blockIdx.x * 256 + threadIdx.x;
    if (tok >= N_TOK) return;
    float l[8], p[8];
    float mx = -1e30f;
#pragma unroll
    for (int e = 0; e < 8; ++e) { l[e] = logits[(size_t)tok * 8 + e]; mx = fmaxf(mx, l[e]); }
    float sum = 0.f;
#pragma unroll
    for (int e = 0; e < 8; ++e) { p[e] = __expf(l[e] - mx); sum += p[e]; }
    float inv = 1.f / sum;
#pragma unroll
    for (int e = 0; e < 8; ++e) p[e] *= inv;
    const size_t NEC = (size_t)N_TOK * E_EXP * CAPV;
    float* probs_out = out + 2 * NEC;
#pragma unroll
    for (int e = 0; e < 8; ++e) probs_out[(size_t)tok * 8 + e] = p[e];
    int i1 = 0;
#pragma unroll
    for (int e = 1; e < 8; ++e) if (p[e] > p[i1]) i1 = e;
    int i2 = -1;
#pragma unroll
    for (int e = 0; e < 8; ++e) {
        if (e == i1) continue;
        if (i2 < 0 || p[e] > p[i2]) i2 = e;
    }
    float v1 = p[i1], v2 = p[i2], tv = v1 + v2;
    size_t base = (size_t)tok * E_EXP * CAPV;
    out[base + (size_t)i1 * CAPV] = 1.f;
    out[base + (size_t)i2 * CAPV] = 1.f;
    out[NEC + base + (size_t)i1 * CAPV] = v1 / tv;
    out[NEC + base + (size_t)i2 * CAPV] = v2 / tv;
}

// ---------------------------------------------------------------- aux loss
__global__ void aux_k(const float* __restrict__ probs, float* __restrict__ out_aux) {
    __shared__ float part[256];
    int tid = threadIdx.x;
    int e = tid & 7, chunk = tid >> 3;
    float s = 0.f;
    for (int t = chunk * 128; t < (chunk + 1) * 128; ++t)
        s += probs[(size_t)t * 8 + e];
    part[tid] = s;
    __syncthreads();
    if (tid < 8) {
        float tot = 0.f;
        for (int c = 0; c < 32; ++c) tot += part[c * 8 + e];
        part[tid] = tot / (float)N_TOK;
    }
    __syncthreads();
    if (tid == 0) {
        float aux = 0.f;
        for (int e2 = 0; e2 < 8; ++e2) {
            float pm = part[e2];
            aux += pm * logf(pm * 8.f + 1e-9f);
        }
        *out_aux = aux;
    }
}

// ---------------------------------------------------------------- launch
extern "C" void kernel_launch(void* const* d_in, const int* in_sizes, int n_in,
                              void* d_out, int out_size, void* d_ws, size_t ws_size,
                              hipStream_t stream) {
    const float* hid = (const float*)d_in[0];
    const float* pos = (const float*)d_in[1];
    const float* We1 = (const float*)d_in[2];
    const float* be1 = (const float*)d_in[3];
    const float* We2 = (const float*)d_in[4];
    const float* be2 = (const float*)d_in[5];
    const float* Ws1 = (const float*)d_in[6];
    const float* bs1 = (const float*)d_in[7];
    const float* Ws2 = (const float*)d_in[8];
    const float* bs2 = (const float*)d_in[9];
    const float* Wq  = (const float*)d_in[10]; const float* bq = (const float*)d_in[11];
    const float* Wk  = (const float*)d_in[12]; const float* bk = (const float*)d_in[13];
    const float* Wv  = (const float*)d_in[14]; const float* bv = (const float*)d_in[15];
    const float* Wo  = (const float*)d_in[16]; const float* bo = (const float*)d_in[17];
    const float* Wr1 = (const float*)d_in[18]; const float* br1 = (const float*)d_in[19];
    const float* Wr2 = (const float*)d_in[20]; const float* br2 = (const float*)d_in[21];

    float* out = (float*)d_out;
    char* base = (char*)d_ws;
    const size_t AC   = (size_t)N_TOK * H_DIM;          // 4.19M elems
    const size_t SPC  = AC * 2;                         // 8.39MB per split comp
    const size_t FB   = AC * 4;                         // 16.8MB f32 buffer
    unsigned short* B1hi = (unsigned short*)(base);
    unsigned short* B1lo = (unsigned short*)(base + SPC);
    unsigned short* B2hi = (unsigned short*)(base + FB);
    unsigned short* B2lo = (unsigned short*)(base + FB + SPC);
    float* qb = (float*)(base + 2 * FB);
    float* kb = (float*)(base + 3 * FB);
    float* vb = (float*)(base + 4 * FB);
    unsigned short* Whi = (unsigned short*)(base + 5 * FB);
    unsigned short* Wlo = (unsigned short*)(base + 5 * FB + (size_t)1024 * 1024 * 2);
    float* seas24  = (float*)(base + 5 * FB + (size_t)1024 * 1024 * 4);
    float* seasons = seas24 + 6144;
    float* logits  = seasons + 2048;

    const size_t NEC = (size_t)N_TOK * E_EXP * CAPV;

    static bool attr_set = false;
    if (!attr_set) {
        hipFuncSetAttribute((const void*)attn_k,
                            hipFuncAttributeMaxDynamicSharedMemorySize,
                            ATTN_LDS_BYTES);
        attr_set = true;
    }

    hipMemsetAsync(d_out, 0, (size_t)out_size * sizeof(float), stream);

    season_k<<<8, 256, 0, stream>>>(seasons);
    seas24_k<<<24, 256, 0, stream>>>(seasons, Ws1, bs1, Ws2, bs2, seas24);
    convert_split_k<<<4096, 256, 0, stream>>>(hid, B1hi, B1lo, (int)(AC / 4));

    dim3 gg(16, 32), blk(256);
    dim3 wg(16, 16);

    // G1: e1 = relu(hid@We1 + be1 + t*rowT + s*rowS)  -> B2 split
    wconv_t_k<<<wg, blk, 0, stream>>>(We1, Whi, Wlo);
    gemm_split<1, 0, 1><<<gg, blk, 0, stream>>>(B1hi, B1lo, Whi, Wlo, be1,
        nullptr, B2hi, B2lo,
        We1 + (size_t)1024 * 1024, We1 + (size_t)1025 * 1024, seasons, nullptr, nullptr);
    // G2: x = e1@We2 + be2 + pos + seas  -> B1 split
    wconv_t_k<<<wg, blk, 0, stream>>>(We2, Whi, Wlo);
    gemm_split<2, 0, 1><<<gg, blk, 0, stream>>>(B2hi, B2lo, Whi, Wlo, be2,
        nullptr, B1hi, B1lo, nullptr, nullptr, nullptr, pos, seas24);
    // G3/4/5: q,k,v f32
    wconv_t_k<<<wg, blk, 0, stream>>>(Wq, Whi, Wlo);
    gemm_split<0, 1, 0><<<gg, blk, 0, stream>>>(B1hi, B1lo, Whi, Wlo, bq,
        qb, nullptr, nullptr, nullptr, nullptr, nullptr, nullptr, nullptr);
    wconv_t_k<<<wg, blk, 0, stream>>>(Wk, Whi, Wlo);
    gemm_split<0, 1, 0><<<gg, blk, 0, stream>>>(B1hi, B1lo, Whi, Wlo, bk,
        kb, nullptr, nullptr, nullptr, nullptr, nullptr, nullptr, nullptr);
    wconv_t_k<<<wg, blk, 0, stream>>>(Wv, Whi, Wlo);
    gemm_split<0, 1, 0><<<gg, blk, 0, stream>>>(B1hi, B1lo, Whi, Wlo, bv,
        vb, nullptr, nullptr, nullptr, nullptr, nullptr, nullptr, nullptr);

    attn_k<<<dim3(32, 16), 256, ATTN_LDS_BYTES, stream>>>(qb, kb, vb, B1hi, B1lo);

    // G6: x2 = ctx@Wo + bo -> B2 split
    wconv_t_k<<<wg, blk, 0, stream>>>(Wo, Whi, Wlo);
    gemm_split<0, 0, 1><<<gg, blk, 0, stream>>>(B1hi, B1lo, Whi, Wlo, bo,
        nullptr, B2hi, B2lo, nullptr, nullptr, nullptr, nullptr, nullptr);
    // G7: h1 = relu(x2@Wr1 + br1) -> qb f32
    wconv_t_k<<<wg, blk, 0, stream>>>(Wr1, Whi, Wlo);
    gemm_split<3, 1, 0><<<gg, blk, 0, stream>>>(B2hi, B2lo, Whi, Wlo, br1,
        qb, nullptr, nullptr, nullptr, nullptr, nullptr, nullptr, nullptr);

    logits_k<<<128, 256, 0, stream>>>(qb, Wr2, br2, logits);
    topk_k<<<16, 256, 0, stream>>>(logits, out);
    aux_k<<<1, 256, 0, stream>>>(out + 2 * NEC, out + 2 * NEC + (size_t)N_TOK * E_EXP);
}

// Round 4
// 755.259 us; speedup vs baseline: 3.0083x; 1.4355x over previous
//
#include <hip/hip_runtime.h>
#include <hip/hip_fp16.h>
#include <math.h>

#define N_TOK 4096
#define S_LEN 2048
#define H_DIM 1024
#define E_EXP 8
#define CAPV  1536
#define NHEAD 8
#define HDHD  128

typedef __attribute__((ext_vector_type(8))) _Float16 v8h;
typedef __attribute__((ext_vector_type(4))) float v4f;

__device__ __forceinline__ void splitf16(float v, unsigned short& h, unsigned short& l) {
    __half hh = __float2half(v);
    h = __half_as_ushort(hh);
    l = __half_as_ushort(__float2half(v - __half2float(hh)));
}

__device__ __forceinline__ void gld_lds16(const void* g, void* l) {
    __builtin_amdgcn_global_load_lds(
        (const __attribute__((address_space(1))) unsigned int*)g,
        (__attribute__((address_space(3))) unsigned int*)l,
        16, 0, 0);
}

// ---------------------------------------------------------------- seasons
__global__ void season_k(float* seasons) {
    int s = blockIdx.x * 256 + threadIdx.x;
    if (s < S_LEN) {
        double a = (double)s * 2.0 * M_PI / 24.0;
        seasons[s] = (float)sin(a);
    }
}

__global__ void seas24_k(const float* __restrict__ seasons,
                         const float* __restrict__ Ws1, const float* __restrict__ bs1,
                         const float* __restrict__ Ws2, const float* __restrict__ bs2,
                         float* __restrict__ seas24) {
    __shared__ float hbuf[256];
    int m = blockIdx.x;
    float sv = seasons[m];
    int j = threadIdx.x;
    hbuf[j] = fmaxf(sv * Ws1[j] + bs1[j], 0.f);
    __syncthreads();
    float acc = bs2[j];
    for (int i = 0; i < 256; ++i) acc = fmaf(hbuf[i], Ws2[i * 256 + j], acc);
    seas24[m * 256 + j] = acc;
}

// ---------------------------------------------------------------- f32 -> f16 hi/lo split
__global__ void convert_split_k(const float* __restrict__ in,
                                unsigned short* __restrict__ hi,
                                unsigned short* __restrict__ lo, int n4) {
    int i = blockIdx.x * 256 + threadIdx.x;
    if (i >= n4) return;
    float4 v = ((const float4*)in)[i];
    ushort4 h, l;
    splitf16(v.x, h.x, l.x);
    splitf16(v.y, h.y, l.y);
    splitf16(v.z, h.z, l.z);
    splitf16(v.w, h.w, l.w);
    ((ushort4*)hi)[i] = h;
    ((ushort4*)lo)[i] = l;
}

// ---------------------------------------------------------------- W[1024][1024] -> W^T hi/lo f16
__global__ __launch_bounds__(256) void wconv_t_k(const float* __restrict__ W,
                                                 unsigned short* __restrict__ Thi,
                                                 unsigned short* __restrict__ Tlo) {
    __shared__ unsigned short Hs[64][65];
    __shared__ unsigned short Ls[64][65];
    int k0 = blockIdx.y * 64, n0 = blockIdx.x * 64;
    int tid = threadIdx.x;
#pragma unroll
    for (int i = 0; i < 4; ++i) {
        int idx = tid + i * 256;
        int kk = idx >> 4, n4 = idx & 15;
        float4 v = *(const float4*)(W + (size_t)(k0 + kk) * 1024 + n0 + n4 * 4);
        unsigned short h, l;
        splitf16(v.x, h, l); Hs[n4 * 4 + 0][kk] = h; Ls[n4 * 4 + 0][kk] = l;
        splitf16(v.y, h, l); Hs[n4 * 4 + 1][kk] = h; Ls[n4 * 4 + 1][kk] = l;
        splitf16(v.z, h, l); Hs[n4 * 4 + 2][kk] = h; Ls[n4 * 4 + 2][kk] = l;
        splitf16(v.w, h, l); Hs[n4 * 4 + 3][kk] = h; Ls[n4 * 4 + 3][kk] = l;
    }
    __syncthreads();
#pragma unroll
    for (int i = 0; i < 4; ++i) {
        int idx = tid + i * 256;
        int n = idx >> 4, k4 = idx & 15;
        ushort4 h = make_ushort4(Hs[n][k4 * 4], Hs[n][k4 * 4 + 1], Hs[n][k4 * 4 + 2], Hs[n][k4 * 4 + 3]);
        ushort4 l = make_ushort4(Ls[n][k4 * 4], Ls[n][k4 * 4 + 1], Ls[n][k4 * 4 + 2], Ls[n][k4 * 4 + 3]);
        *(ushort4*)(Thi + (size_t)(n0 + n) * 1024 + k0 + k4 * 4) = h;
        *(ushort4*)(Tlo + (size_t)(n0 + n) * 1024 + k0 + k4 * 4) = l;
    }
}

// ---------------------------------------------------------------- split-f16 MFMA GEMM
// MODE 0:+bias | 1:relu(+bias+t*rowT+s*rowS) | 2:+bias+pos+seas24 | 3:relu(+bias)
// EMITF: f32 C. EMITS: split f16 Chi/Clo (scaled by escale). EMITT: split f16,
// transposed per-head layout Vt[(b*8+h)*128+d][2048 s] (for attention V/B-frags).
template <int MODE, int EMITF, int EMITS, int EMITT>
__global__ __launch_bounds__(256, 2) void gemm_split(
    const unsigned short* __restrict__ Ahi, const unsigned short* __restrict__ Alo,
    const unsigned short* __restrict__ WThi, const unsigned short* __restrict__ WTlo,
    const float* __restrict__ bias, float* __restrict__ Cf,
    unsigned short* __restrict__ Chi, unsigned short* __restrict__ Clo,
    const float* __restrict__ rowT, const float* __restrict__ rowS,
    const float* __restrict__ seasons, const float* __restrict__ pos,
    const float* __restrict__ seas24, float escale) {
    __shared__ unsigned short As[128 * 32];
    __shared__ unsigned short Bs[64 * 32];
    int tid = threadIdx.x;
    int lane = tid & 63, w = tid >> 6;
    int l15 = lane & 15, l16 = lane >> 4;
    int wm = (w >> 1) * 64, wn = (w & 1) * 32;
    int m0 = blockIdx.y * 128, n0 = blockIdx.x * 64;

    int ac0 = w * 128 + lane;
    int ac1 = ac0 + 64;
    int bc  = w * 64 + lane;
    int ar0 = ac0 >> 2, ar1 = ac1 >> 2, bn = bc >> 2;
    size_t a_src0 = (size_t)(m0 + ar0) * 1024 + (((ac0 & 3) ^ (ar0 & 3)) * 8);
    size_t a_src1 = (size_t)(m0 + ar1) * 1024 + (((ac1 & 3) ^ (ar1 & 3)) * 8);
    size_t b_src  = (size_t)(n0 + bn) * 1024 + (((bc & 3) ^ (bn & 3)) * 8);
    unsigned short* a_lds0 = &As[ac0 * 8];
    unsigned short* a_lds1 = &As[ac1 * 8];
    unsigned short* b_lds  = &Bs[bc * 8];

    int a_off[4], b_off[2];
#pragma unroll
    for (int mi = 0; mi < 4; ++mi) {
        int row = wm + mi * 16 + l15;
        a_off[mi] = row * 32 + ((l16 ^ (row & 3)) * 8);
    }
#pragma unroll
    for (int ni = 0; ni < 2; ++ni) {
        int n = wn + ni * 16 + l15;
        b_off[ni] = n * 32 + ((l16 ^ (n & 3)) * 8);
    }

    v4f acc[4][2] = {};
    const unsigned short* aph[3] = {Ahi, Alo, Ahi};
    const unsigned short* wph[3] = {WThi, WThi, WTlo};

    for (int ph = 0; ph < 3; ++ph) {
        const unsigned short* __restrict__ pa = aph[ph];
        const unsigned short* __restrict__ pw = wph[ph];
        for (int k0 = 0; k0 < 1024; k0 += 32) {
            __syncthreads();
            gld_lds16(pa + a_src0 + k0, a_lds0);
            gld_lds16(pa + a_src1 + k0, a_lds1);
            gld_lds16(pw + b_src + k0, b_lds);
            __syncthreads();
            v8h a0 = *(const v8h*)&As[a_off[0]];
            v8h a1 = *(const v8h*)&As[a_off[1]];
            v8h a2 = *(const v8h*)&As[a_off[2]];
            v8h a3 = *(const v8h*)&As[a_off[3]];
            v8h b0 = *(const v8h*)&Bs[b_off[0]];
            v8h b1 = *(const v8h*)&Bs[b_off[1]];
            acc[0][0] = __builtin_amdgcn_mfma_f32_16x16x32_f16(a0, b0, acc[0][0], 0, 0, 0);
            acc[0][1] = __builtin_amdgcn_mfma_f32_16x16x32_f16(a0, b1, acc[0][1], 0, 0, 0);
            acc[1][0] = __builtin_amdgcn_mfma_f32_16x16x32_f16(a1, b0, acc[1][0], 0, 0, 0);
            acc[1][1] = __builtin_amdgcn_mfma_f32_16x16x32_f16(a1, b1, acc[1][1], 0, 0, 0);
            acc[2][0] = __builtin_amdgcn_mfma_f32_16x16x32_f16(a2, b0, acc[2][0], 0, 0, 0);
            acc[2][1] = __builtin_amdgcn_mfma_f32_16x16x32_f16(a2, b1, acc[2][1], 0, 0, 0);
            acc[3][0] = __builtin_amdgcn_mfma_f32_16x16x32_f16(a3, b0, acc[3][0], 0, 0, 0);
            acc[3][1] = __builtin_amdgcn_mfma_f32_16x16x32_f16(a3, b1, acc[3][1], 0, 0, 0);
        }
    }

    if (EMITT) {
        // transposed split emit: Vt[(b*8+h)*128+d][s], 4 consecutive s per lane
#pragma unroll
        for (int mi = 0; mi < 4; ++mi) {
            int row0 = m0 + wm + mi * 16 + l16 * 4;
            int bb = row0 >> 11, ss = row0 & 2047;
#pragma unroll
            for (int ni = 0; ni < 2; ++ni) {
                int col = n0 + wn + ni * 16 + l15;
                int hh = col >> 7, dd = col & 127;
                size_t base = ((size_t)((bb * 8 + hh) * 128 + dd)) * 2048 + ss;
                ushort4 vh, vl;
                float v0 = acc[mi][ni][0] + bias[col];
                float v1 = acc[mi][ni][1] + bias[col];
                float v2 = acc[mi][ni][2] + bias[col];
                float v3 = acc[mi][ni][3] + bias[col];
                splitf16(v0, vh.x, vl.x);
                splitf16(v1, vh.y, vl.y);
                splitf16(v2, vh.z, vl.z);
                splitf16(v3, vh.w, vl.w);
                *(ushort4*)(Chi + base) = vh;
                *(ushort4*)(Clo + base) = vl;
            }
        }
    } else {
#pragma unroll
        for (int mi = 0; mi < 4; ++mi) {
#pragma unroll
            for (int r = 0; r < 4; ++r) {
                int row = m0 + wm + mi * 16 + l16 * 4 + r;
                int s = row & (S_LEN - 1);
                float tval = 0.f, seval = 0.f;
                if (MODE == 1) { tval = (float)s; seval = seasons[s]; }
#pragma unroll
                for (int ni = 0; ni < 2; ++ni) {
                    int col = n0 + wn + ni * 16 + l15;
                    float v = acc[mi][ni][r] + bias[col];
                    if (MODE == 1) v += tval * rowT[col] + seval * rowS[col];
                    if (MODE == 2) v += pos[(size_t)s * 1024 + col] + seas24[(s % 24) * 256 + (col & 255)];
                    if (MODE == 1 || MODE == 3) v = fmaxf(v, 0.f);
                    size_t o = (size_t)row * 1024 + col;
                    if (EMITF) Cf[o] = v;
                    if (EMITS) {
                        unsigned short hu, lu;
                        splitf16(v * escale, hu, lu);
                        Chi[o] = hu; Clo[o] = lu;
                    }
                }
            }
        }
    }
}

// ---------------------------------------------------------------- MFMA attention
// grid (S/64, B*NH), block 256 = 4 waves; wave owns 16 q-rows; KVB=32.
// Q in registers (split); K [32][128], Vt [128][32] split in LDS (swizzled);
// P packed (hi|lo<<16) u32 in LDS. All MFMA f16-split (3 terms), f32 accum.
__global__ __launch_bounds__(256, 2) void attn_mfma_k(
    const unsigned short* __restrict__ qhi, const unsigned short* __restrict__ qlo,
    const unsigned short* __restrict__ khi, const unsigned short* __restrict__ klo,
    const unsigned short* __restrict__ vthi, const unsigned short* __restrict__ vtlo,
    unsigned short* __restrict__ ctx_hi, unsigned short* __restrict__ ctx_lo) {
    __shared__ unsigned short Ks_hi[32 * 128];
    __shared__ unsigned short Ks_lo[32 * 128];
    __shared__ unsigned short Vs_hi[128 * 32];
    __shared__ unsigned short Vs_lo[128 * 32];
    __shared__ unsigned int   Ps[64 * 32];

    int bh = blockIdx.y;
    int b = bh >> 3, h = bh & 7;
    int q0 = blockIdx.x * 64;
    int tid = threadIdx.x;
    int lane = tid & 63, w = tid >> 6;
    int l15 = lane & 15, l16 = lane >> 4;
    int wm = w * 16;

    // Q fragments in registers (A-layout: row=l15, k-chunk=l16)
    v8h qa_h[4], qa_l[4];
    {
        size_t qrow = (size_t)(b * S_LEN + q0 + wm + l15) * H_DIM + h * HDHD;
#pragma unroll
        for (int ks = 0; ks < 4; ++ks) {
            qa_h[ks] = *(const v8h*)(qhi + qrow + ks * 32 + l16 * 8);
            qa_l[ks] = *(const v8h*)(qlo + qrow + ks * 32 + l16 * 8);
        }
    }

    // staging addresses (chunk = tid and tid+256 per buffer), pre-swizzled source
    int ktok1 = tid >> 4, kslot1 = tid & 15;
    int ktok2 = ktok1 + 16;
    size_t ksrc1 = (size_t)(b * S_LEN + ktok1) * H_DIM + h * HDHD + ((kslot1 ^ (ktok1 & 7)) * 8);
    size_t ksrc2 = (size_t)(b * S_LEN + ktok2) * H_DIM + h * HDHD + ((kslot1 ^ (ktok2 & 7)) * 8);
    int vd1 = tid >> 2, vslot1 = tid & 3;
    int vd2 = vd1 + 64;
    size_t vsrc1 = (size_t)(bh * HDHD + vd1) * S_LEN + ((vslot1 ^ ((vd1 >> 1) & 3)) * 8);
    size_t vsrc2 = (size_t)(bh * HDHD + vd2) * S_LEN + ((vslot1 ^ ((vd2 >> 1) & 3)) * 8);

    v4f accO[8] = {};
    float mreg[4] = {-1e30f, -1e30f, -1e30f, -1e30f};
    float lreg[4] = {};

    for (int kt = 0; kt < S_LEN; kt += 32) {
        __syncthreads();
        size_t koff = (size_t)kt * H_DIM;
        gld_lds16(khi + ksrc1 + koff, &Ks_hi[tid * 8]);
        gld_lds16(khi + ksrc2 + koff, &Ks_hi[(tid + 256) * 8]);
        gld_lds16(klo + ksrc1 + koff, &Ks_lo[tid * 8]);
        gld_lds16(klo + ksrc2 + koff, &Ks_lo[(tid + 256) * 8]);
        gld_lds16(vthi + vsrc1 + kt, &Vs_hi[tid * 8]);
        gld_lds16(vthi + vsrc2 + kt, &Vs_hi[(tid + 256) * 8]);
        gld_lds16(vtlo + vsrc1 + kt, &Vs_lo[tid * 8]);
        gld_lds16(vtlo + vsrc2 + kt, &Vs_lo[(tid + 256) * 8]);
        __syncthreads();

        // ---- QK^T: S[16 q][32 tok]
        v4f s0 = {}, s1 = {};
#pragma unroll
        for (int ks = 0; ks < 4; ++ks) {
#pragma unroll
            for (int nt = 0; nt < 2; ++nt) {
                int tok = nt * 16 + l15;
                int slot = (ks * 4 + l16) ^ (tok & 7);
                v8h bhf = *(const v8h*)&Ks_hi[tok * 128 + slot * 8];
                v8h blf = *(const v8h*)&Ks_lo[tok * 128 + slot * 8];
                v4f& ss = nt ? s1 : s0;
                ss = __builtin_amdgcn_mfma_f32_16x16x32_f16(qa_h[ks], bhf, ss, 0, 0, 0);
                ss = __builtin_amdgcn_mfma_f32_16x16x32_f16(qa_l[ks], bhf, ss, 0, 0, 0);
                ss = __builtin_amdgcn_mfma_f32_16x16x32_f16(qa_h[ks], blf, ss, 0, 0, 0);
            }
        }

        // ---- online softmax (C-layout: row q = l16*4+r, col tok = l15)
        float p0[4], p1[4], alpha[4];
#pragma unroll
        for (int r = 0; r < 4; ++r) {
            float tmax = fmaxf(s0[r], s1[r]);
            tmax = fmaxf(tmax, __shfl_xor(tmax, 1));
            tmax = fmaxf(tmax, __shfl_xor(tmax, 2));
            tmax = fmaxf(tmax, __shfl_xor(tmax, 4));
            tmax = fmaxf(tmax, __shfl_xor(tmax, 8));
            float mnew = fmaxf(mreg[r], tmax);
            alpha[r] = __expf(mreg[r] - mnew);
            p0[r] = __expf(s0[r] - mnew);
            p1[r] = __expf(s1[r] - mnew);
            float lt = p0[r] + p1[r];
            lt += __shfl_xor(lt, 1);
            lt += __shfl_xor(lt, 2);
            lt += __shfl_xor(lt, 4);
            lt += __shfl_xor(lt, 8);
            lreg[r] = lreg[r] * alpha[r] + lt;
            mreg[r] = mnew;
        }
#pragma unroll
        for (int nt = 0; nt < 8; ++nt)
#pragma unroll
            for (int r = 0; r < 4; ++r) accO[nt][r] *= alpha[r];

        // ---- P -> LDS packed u32 (hi | lo<<16), swizzled
#pragma unroll
        for (int r = 0; r < 4; ++r) {
            int qq = wm + l16 * 4 + r;
            unsigned short ph, pl;
            splitf16(p0[r], ph, pl);
            int k0i = l15;
            Ps[qq * 32 + ((((k0i >> 2) ^ (qq & 7)) << 2) | (k0i & 3))] =
                (unsigned)ph | ((unsigned)pl << 16);
            splitf16(p1[r], ph, pl);
            int k1i = 16 + l15;
            Ps[qq * 32 + ((((k1i >> 2) ^ (qq & 7)) << 2) | (k1i & 3))] =
                (unsigned)ph | ((unsigned)pl << 16);
        }
        __syncthreads();

        // ---- PV: O[16 q][128 d] += P[16 q][32 k] * V[32 k][128 d]
        int qq = wm + l15;
        int sA = (l16 * 2) ^ (qq & 7);
        int sB = (l16 * 2 + 1) ^ (qq & 7);
        uint4 ua = *(const uint4*)&Ps[qq * 32 + sA * 4];
        uint4 ub = *(const uint4*)&Ps[qq * 32 + sB * 4];
        uint4 ahw, alw;
        ahw.x = (ua.x & 0xffffu) | (ua.y << 16);
        ahw.y = (ua.z & 0xffffu) | (ua.w << 16);
        ahw.z = (ub.x & 0xffffu) | (ub.y << 16);
        ahw.w = (ub.z & 0xffffu) | (ub.w << 16);
        alw.x = (ua.x >> 16) | (ua.y & 0xffff0000u);
        alw.y = (ua.z >> 16) | (ua.w & 0xffff0000u);
        alw.z = (ub.x >> 16) | (ub.w & 0xffff0000u & 0u) | (ub.y & 0xffff0000u);
        alw.w = (ub.z >> 16) | (ub.w & 0xffff0000u);
        // fix z (typo-proof explicit):
        alw.z = (ub.x >> 16) | (ub.y & 0xffff0000u);
        v8h pA_h = __builtin_bit_cast(v8h, ahw);
        v8h pA_l = __builtin_bit_cast(v8h, alw);
#pragma unroll
        for (int nt = 0; nt < 8; ++nt) {
            int d = nt * 16 + l15;
            int slot = l16 ^ ((d >> 1) & 3);
            v8h vhf = *(const v8h*)&Vs_hi[d * 32 + slot * 8];
            v8h vlf = *(const v8h*)&Vs_lo[d * 32 + slot * 8];
            accO[nt] = __builtin_amdgcn_mfma_f32_16x16x32_f16(pA_h, vhf, accO[nt], 0, 0, 0);
            accO[nt] = __builtin_amdgcn_mfma_f32_16x16x32_f16(pA_l, vhf, accO[nt], 0, 0, 0);
            accO[nt] = __builtin_amdgcn_mfma_f32_16x16x32_f16(pA_h, vlf, accO[nt], 0, 0, 0);
        }
        __syncthreads();
    }

    // ---- epilogue: split ctx out
    float linv[4];
#pragma unroll
    for (int r = 0; r < 4; ++r) linv[r] = 1.f / lreg[r];
#pragma unroll
    for (int nt = 0; nt < 8; ++nt) {
#pragma unroll
        for (int r = 0; r < 4; ++r) {
            size_t o = (size_t)(b * S_LEN + q0 + wm + l16 * 4 + r) * H_DIM + h * HDHD + nt * 16 + l15;
            unsigned short hu, lu;
            splitf16(accO[nt][r] * linv[r], hu, lu);
            ctx_hi[o] = hu;
            ctx_lo[o] = lu;
        }
    }
}

// ---------------------------------------------------------------- router logits
__global__ void logits_k(const float* __restrict__ h1, const float* __restrict__ Wr2,
                         const float* __restrict__ br2, float* __restrict__ logits) {
    int tid = threadIdx.x;
    int tok = blockIdx.x * 32 + (tid >> 3);
    int e = tid & 7;
    const float* hrow = h1 + (size_t)tok * 1024;
    float acc = br2[e];
    for (int i = 0; i < 1024; ++i) acc = fmaf(hrow[i], Wr2[i * 8 + e], acc);
    logits[(size_t)tok * 8 + e] = acc;
}

// ---------------------------------------------------------------- softmax + top2 + scatter
__global__ void topk_k(const float* __restrict__ logits, float* __restrict__ out) {
    int tok = blockIdx.x * 256 + threadIdx.x;
    if (tok >= N_TOK) return;
    float l[8], p[8];
    float mx = -1e30f;
#pragma unroll
    for (int e = 0; e < 8; ++e) { l[e] = logits[(size_t)tok * 8 + e]; mx = fmaxf(mx, l[e]); }
    float sum = 0.f;
#pragma unroll
    for (int e = 0; e < 8; ++e) { p[e] = __expf(l[e] - mx); sum += p[e]; }
    float inv = 1.f / sum;
#pragma unroll
    for (int e = 0; e < 8; ++e) p[e] *= inv;
    const size_t NEC = (size_t)N_TOK * E_EXP * CAPV;
    float* probs_out = out + 2 * NEC;
#pragma unroll
    for (int e = 0; e < 8; ++e) probs_out[(size_t)tok * 8 + e] = p[e];
    int i1 = 0;
#pragma unroll
    for (int e = 1; e < 8; ++e) if (p[e] > p[i1]) i1 = e;
    int i2 = -1;
#pragma unroll
    for (int e = 0; e < 8; ++e) {
        if (e == i1) continue;
        if (i2 < 0 || p[e] > p[i2]) i2 = e;
    }
    float v1 = p[i1], v2 = p[i2], tv = v1 + v2;
    size_t base = (size_t)tok * E_EXP * CAPV;
    out[base + (size_t)i1 * CAPV] = 1.f;
    out[base + (size_t)i2 * CAPV] = 1.f;
    out[NEC + base + (size_t)i1 * CAPV] = v1 / tv;
    out[NEC + base + (size_t)i2 * CAPV] = v2 / tv;
}

// ---------------------------------------------------------------- aux loss
__global__ void aux_k(const float* __restrict__ probs, float* __restrict__ out_aux) {
    __shared__ float part[256];
    int tid = threadIdx.x;
    int e = tid & 7, chunk = tid >> 3;
    float s = 0.f;
    for (int t = chunk * 128; t < (chunk + 1) * 128; ++t)
        s += probs[(size_t)t * 8 + e];
    part[tid] = s;
    __syncthreads();
    if (tid < 8) {
        float tot = 0.f;
        for (int c = 0; c < 32; ++c) tot += part[c * 8 + e];
        part[tid] = tot / (float)N_TOK;
    }
    __syncthreads();
    if (tid == 0) {
        float aux = 0.f;
        for (int e2 = 0; e2 < 8; ++e2) {
            float pm = part[e2];
            aux += pm * logf(pm * 8.f + 1e-9f);
        }
        *out_aux = aux;
    }
}

// ---------------------------------------------------------------- launch
extern "C" void kernel_launch(void* const* d_in, const int* in_sizes, int n_in,
                              void* d_out, int out_size, void* d_ws, size_t ws_size,
                              hipStream_t stream) {
    const float* hid = (const float*)d_in[0];
    const float* pos = (const float*)d_in[1];
    const float* We1 = (const float*)d_in[2];
    const float* be1 = (const float*)d_in[3];
    const float* We2 = (const float*)d_in[4];
    const float* be2 = (const float*)d_in[5];
    const float* Ws1 = (const float*)d_in[6];
    const float* bs1 = (const float*)d_in[7];
    const float* Ws2 = (const float*)d_in[8];
    const float* bs2 = (const float*)d_in[9];
    const float* Wq  = (const float*)d_in[10]; const float* bq = (const float*)d_in[11];
    const float* Wk  = (const float*)d_in[12]; const float* bk = (const float*)d_in[13];
    const float* Wv  = (const float*)d_in[14]; const float* bv = (const float*)d_in[15];
    const float* Wo  = (const float*)d_in[16]; const float* bo = (const float*)d_in[17];
    const float* Wr1 = (const float*)d_in[18]; const float* br1 = (const float*)d_in[19];
    const float* Wr2 = (const float*)d_in[20]; const float* br2 = (const float*)d_in[21];

    float* out = (float*)d_out;
    char* base = (char*)d_ws;
    const size_t AC  = (size_t)N_TOK * H_DIM;
    const size_t SPC = AC * 2;          // 8.39 MB (one split component)
    const size_t FB  = AC * 4;          // 16.8 MB (split pair)
    unsigned short* B1hi = (unsigned short*)(base);
    unsigned short* B1lo = (unsigned short*)(base + SPC);
    unsigned short* B2hi = (unsigned short*)(base + FB);
    unsigned short* B2lo = (unsigned short*)(base + FB + SPC);
    unsigned short* Qhi  = (unsigned short*)(base + 2 * FB);
    unsigned short* Qlo  = (unsigned short*)(base + 2 * FB + SPC);
    unsigned short* Khi  = (unsigned short*)(base + 3 * FB);
    unsigned short* Klo  = (unsigned short*)(base + 3 * FB + SPC);
    unsigned short* VThi = (unsigned short*)(base + 4 * FB);
    unsigned short* VTlo = (unsigned short*)(base + 4 * FB + SPC);
    unsigned short* Whi  = (unsigned short*)(base + 5 * FB);
    unsigned short* Wlo  = (unsigned short*)(base + 5 * FB + (size_t)1024 * 1024 * 2);
    float* h1f     = (float*)(base + 3 * FB);   // reuses K region (free after attn)
    float* seas24  = (float*)(base + 5 * FB + (size_t)1024 * 1024 * 4);
    float* seasons = seas24 + 6144;
    float* logits  = seasons + 2048;

    const size_t NEC = (size_t)N_TOK * E_EXP * CAPV;
    const float QSCALE = 0.08838834764831845f;   // 1/sqrt(128)

    hipMemsetAsync(d_out, 0, (size_t)out_size * sizeof(float), stream);

    season_k<<<8, 256, 0, stream>>>(seasons);
    seas24_k<<<24, 256, 0, stream>>>(seasons, Ws1, bs1, Ws2, bs2, seas24);
    convert_split_k<<<4096, 256, 0, stream>>>(hid, B1hi, B1lo, (int)(AC / 4));

    dim3 gg(16, 32), blk(256);
    dim3 wg(16, 16);

    // G1: e1 = relu(hid@We1 + be1 + t*rowT + s*rowS)  -> B2 split
    wconv_t_k<<<wg, blk, 0, stream>>>(We1, Whi, Wlo);
    gemm_split<1, 0, 1, 0><<<gg, blk, 0, stream>>>(B1hi, B1lo, Whi, Wlo, be1,
        nullptr, B2hi, B2lo,
        We1 + (size_t)1024 * 1024, We1 + (size_t)1025 * 1024, seasons, nullptr, nullptr, 1.f);
    // G2: x = e1@We2 + be2 + pos + seas -> B1 split
    wconv_t_k<<<wg, blk, 0, stream>>>(We2, Whi, Wlo);
    gemm_split<2, 0, 1, 0><<<gg, blk, 0, stream>>>(B2hi, B2lo, Whi, Wlo, be2,
        nullptr, B1hi, B1lo, nullptr, nullptr, nullptr, pos, seas24, 1.f);
    // G3: q (scaled) -> Q split
    wconv_t_k<<<wg, blk, 0, stream>>>(Wq, Whi, Wlo);
    gemm_split<0, 0, 1, 0><<<gg, blk, 0, stream>>>(B1hi, B1lo, Whi, Wlo, bq,
        nullptr, Qhi, Qlo, nullptr, nullptr, nullptr, nullptr, nullptr, QSCALE);
    // G4: k -> K split
    wconv_t_k<<<wg, blk, 0, stream>>>(Wk, Whi, Wlo);
    gemm_split<0, 0, 1, 0><<<gg, blk, 0, stream>>>(B1hi, B1lo, Whi, Wlo, bk,
        nullptr, Khi, Klo, nullptr, nullptr, nullptr, nullptr, nullptr, 1.f);
    // G5: v -> VT split (transposed per-head)
    wconv_t_k<<<wg, blk, 0, stream>>>(Wv, Whi, Wlo);
    gemm_split<0, 0, 0, 1><<<gg, blk, 0, stream>>>(B1hi, B1lo, Whi, Wlo, bv,
        nullptr, VThi, VTlo, nullptr, nullptr, nullptr, nullptr, nullptr, 1.f);

    attn_mfma_k<<<dim3(32, 16), 256, 0, stream>>>(Qhi, Qlo, Khi, Klo, VThi, VTlo, B2hi, B2lo);

    // G6: x2 = ctx@Wo + bo -> B1 split (B1 free after G5)
    wconv_t_k<<<wg, blk, 0, stream>>>(Wo, Whi, Wlo);
    gemm_split<0, 0, 1, 0><<<gg, blk, 0, stream>>>(B2hi, B2lo, Whi, Wlo, bo,
        nullptr, B1hi, B1lo, nullptr, nullptr, nullptr, nullptr, nullptr, 1.f);
    // G7: h1 = relu(x2@Wr1 + br1) -> h1f f32 (K region, free after attn)
    wconv_t_k<<<wg, blk, 0, stream>>>(Wr1, Whi, Wlo);
    gemm_split<3, 1, 0, 0><<<gg, blk, 0, stream>>>(B1hi, B1lo, Whi, Wlo, br1,
        h1f, nullptr, nullptr, nullptr, nullptr, nullptr, nullptr, nullptr, 1.f);

    logits_k<<<128, 256, 0, stream>>>(h1f, Wr2, br2, logits);
    topk_k<<<16, 256, 0, stream>>>(logits, out);
    aux_k<<<1, 256, 0, stream>>>(out + 2 * NEC, out + 2 * NEC + (size_t)N_TOK * E_EXP);
}

// Round 5
// 672.996 us; speedup vs baseline: 3.3760x; 1.1222x over previous
//
#include <hip/hip_runtime.h>
#include <hip/hip_fp16.h>
#include <math.h>

#define N_TOK 4096
#define S_LEN 2048
#define H_DIM 1024
#define E_EXP 8
#define CAPV  1536
#define NHEAD 8
#define HDHD  128

typedef __attribute__((ext_vector_type(8))) _Float16 v8h;
typedef __attribute__((ext_vector_type(4))) float v4f;

__device__ __forceinline__ void splitf16(float v, unsigned short& h, unsigned short& l) {
    __half hh = __float2half(v);
    h = __half_as_ushort(hh);
    l = __half_as_ushort(__float2half(v - __half2float(hh)));
}

__device__ __forceinline__ void gld_lds16(const void* g, void* l) {
    __builtin_amdgcn_global_load_lds(
        (const __attribute__((address_space(1))) unsigned int*)g,
        (__attribute__((address_space(3))) unsigned int*)l,
        16, 0, 0);
}

// ---------------------------------------------------------------- seasons
__global__ void season_k(float* seasons) {
    int s = blockIdx.x * 256 + threadIdx.x;
    if (s < S_LEN) {
        double a = (double)s * 2.0 * M_PI / 24.0;
        seasons[s] = (float)sin(a);
    }
}

__global__ void seas24_k(const float* __restrict__ seasons,
                         const float* __restrict__ Ws1, const float* __restrict__ bs1,
                         const float* __restrict__ Ws2, const float* __restrict__ bs2,
                         float* __restrict__ seas24) {
    __shared__ float hbuf[256];
    int m = blockIdx.x;
    float sv = seasons[m];
    int j = threadIdx.x;
    hbuf[j] = fmaxf(sv * Ws1[j] + bs1[j], 0.f);
    __syncthreads();
    float acc = bs2[j];
    for (int i = 0; i < 256; ++i) acc = fmaf(hbuf[i], Ws2[i * 256 + j], acc);
    seas24[m * 256 + j] = acc;
}

// ---------------------------------------------------------------- f32 -> f16 hi/lo split
__global__ void convert_split_k(const float* __restrict__ in,
                                unsigned short* __restrict__ hi,
                                unsigned short* __restrict__ lo, int n4) {
    int i = blockIdx.x * 256 + threadIdx.x;
    if (i >= n4) return;
    float4 v = ((const float4*)in)[i];
    ushort4 h, l;
    splitf16(v.x, h.x, l.x);
    splitf16(v.y, h.y, l.y);
    splitf16(v.z, h.z, l.z);
    splitf16(v.w, h.w, l.w);
    ((ushort4*)hi)[i] = h;
    ((ushort4*)lo)[i] = l;
}

// ---------------------------------------------------------------- W[1024][1024] -> W^T hi/lo f16
__global__ __launch_bounds__(256) void wconv_t_k(const float* __restrict__ W,
                                                 unsigned short* __restrict__ Thi,
                                                 unsigned short* __restrict__ Tlo) {
    __shared__ unsigned short Hs[64][65];
    __shared__ unsigned short Ls[64][65];
    int k0 = blockIdx.y * 64, n0 = blockIdx.x * 64;
    int tid = threadIdx.x;
#pragma unroll
    for (int i = 0; i < 4; ++i) {
        int idx = tid + i * 256;
        int kk = idx >> 4, n4 = idx & 15;
        float4 v = *(const float4*)(W + (size_t)(k0 + kk) * 1024 + n0 + n4 * 4);
        unsigned short h, l;
        splitf16(v.x, h, l); Hs[n4 * 4 + 0][kk] = h; Ls[n4 * 4 + 0][kk] = l;
        splitf16(v.y, h, l); Hs[n4 * 4 + 1][kk] = h; Ls[n4 * 4 + 1][kk] = l;
        splitf16(v.z, h, l); Hs[n4 * 4 + 2][kk] = h; Ls[n4 * 4 + 2][kk] = l;
        splitf16(v.w, h, l); Hs[n4 * 4 + 3][kk] = h; Ls[n4 * 4 + 3][kk] = l;
    }
    __syncthreads();
#pragma unroll
    for (int i = 0; i < 4; ++i) {
        int idx = tid + i * 256;
        int n = idx >> 4, k4 = idx & 15;
        ushort4 h = make_ushort4(Hs[n][k4 * 4], Hs[n][k4 * 4 + 1], Hs[n][k4 * 4 + 2], Hs[n][k4 * 4 + 3]);
        ushort4 l = make_ushort4(Ls[n][k4 * 4], Ls[n][k4 * 4 + 1], Ls[n][k4 * 4 + 2], Ls[n][k4 * 4 + 3]);
        *(ushort4*)(Thi + (size_t)(n0 + n) * 1024 + k0 + k4 * 4) = h;
        *(ushort4*)(Tlo + (size_t)(n0 + n) * 1024 + k0 + k4 * 4) = l;
    }
}

// ---------------------------------------------------------------- split-f16 MFMA GEMM
template <int MODE, int EMITF, int EMITS, int EMITT>
__global__ __launch_bounds__(256, 2) void gemm_split(
    const unsigned short* __restrict__ Ahi, const unsigned short* __restrict__ Alo,
    const unsigned short* __restrict__ WThi, const unsigned short* __restrict__ WTlo,
    const float* __restrict__ bias, float* __restrict__ Cf,
    unsigned short* __restrict__ Chi, unsigned short* __restrict__ Clo,
    const float* __restrict__ rowT, const float* __restrict__ rowS,
    const float* __restrict__ seasons, const float* __restrict__ pos,
    const float* __restrict__ seas24, float escale) {
    __shared__ unsigned short As[128 * 32];
    __shared__ unsigned short Bs[64 * 32];
    int tid = threadIdx.x;
    int lane = tid & 63, w = tid >> 6;
    int l15 = lane & 15, l16 = lane >> 4;
    int wm = (w >> 1) * 64, wn = (w & 1) * 32;
    int m0 = blockIdx.y * 128, n0 = blockIdx.x * 64;

    int ac0 = w * 128 + lane;
    int ac1 = ac0 + 64;
    int bc  = w * 64 + lane;
    int ar0 = ac0 >> 2, ar1 = ac1 >> 2, bn = bc >> 2;
    size_t a_src0 = (size_t)(m0 + ar0) * 1024 + (((ac0 & 3) ^ (ar0 & 3)) * 8);
    size_t a_src1 = (size_t)(m0 + ar1) * 1024 + (((ac1 & 3) ^ (ar1 & 3)) * 8);
    size_t b_src  = (size_t)(n0 + bn) * 1024 + (((bc & 3) ^ (bn & 3)) * 8);
    unsigned short* a_lds0 = &As[ac0 * 8];
    unsigned short* a_lds1 = &As[ac1 * 8];
    unsigned short* b_lds  = &Bs[bc * 8];

    int a_off[4], b_off[2];
#pragma unroll
    for (int mi = 0; mi < 4; ++mi) {
        int row = wm + mi * 16 + l15;
        a_off[mi] = row * 32 + ((l16 ^ (row & 3)) * 8);
    }
#pragma unroll
    for (int ni = 0; ni < 2; ++ni) {
        int n = wn + ni * 16 + l15;
        b_off[ni] = n * 32 + ((l16 ^ (n & 3)) * 8);
    }

    v4f acc[4][2] = {};
    const unsigned short* aph[3] = {Ahi, Alo, Ahi};
    const unsigned short* wph[3] = {WThi, WThi, WTlo};

    for (int ph = 0; ph < 3; ++ph) {
        const unsigned short* __restrict__ pa = aph[ph];
        const unsigned short* __restrict__ pw = wph[ph];
        for (int k0 = 0; k0 < 1024; k0 += 32) {
            __syncthreads();
            gld_lds16(pa + a_src0 + k0, a_lds0);
            gld_lds16(pa + a_src1 + k0, a_lds1);
            gld_lds16(pw + b_src + k0, b_lds);
            __syncthreads();
            v8h a0 = *(const v8h*)&As[a_off[0]];
            v8h a1 = *(const v8h*)&As[a_off[1]];
            v8h a2 = *(const v8h*)&As[a_off[2]];
            v8h a3 = *(const v8h*)&As[a_off[3]];
            v8h b0 = *(const v8h*)&Bs[b_off[0]];
            v8h b1 = *(const v8h*)&Bs[b_off[1]];
            acc[0][0] = __builtin_amdgcn_mfma_f32_16x16x32_f16(a0, b0, acc[0][0], 0, 0, 0);
            acc[0][1] = __builtin_amdgcn_mfma_f32_16x16x32_f16(a0, b1, acc[0][1], 0, 0, 0);
            acc[1][0] = __builtin_amdgcn_mfma_f32_16x16x32_f16(a1, b0, acc[1][0], 0, 0, 0);
            acc[1][1] = __builtin_amdgcn_mfma_f32_16x16x32_f16(a1, b1, acc[1][1], 0, 0, 0);
            acc[2][0] = __builtin_amdgcn_mfma_f32_16x16x32_f16(a2, b0, acc[2][0], 0, 0, 0);
            acc[2][1] = __builtin_amdgcn_mfma_f32_16x16x32_f16(a2, b1, acc[2][1], 0, 0, 0);
            acc[3][0] = __builtin_amdgcn_mfma_f32_16x16x32_f16(a3, b0, acc[3][0], 0, 0, 0);
            acc[3][1] = __builtin_amdgcn_mfma_f32_16x16x32_f16(a3, b1, acc[3][1], 0, 0, 0);
        }
    }

    if (EMITT) {
#pragma unroll
        for (int mi = 0; mi < 4; ++mi) {
            int row0 = m0 + wm + mi * 16 + l16 * 4;
            int bb = row0 >> 11, ss = row0 & 2047;
#pragma unroll
            for (int ni = 0; ni < 2; ++ni) {
                int col = n0 + wn + ni * 16 + l15;
                int hh = col >> 7, dd = col & 127;
                size_t base = ((size_t)((bb * 8 + hh) * 128 + dd)) * 2048 + ss;
                ushort4 vh, vl;
                float v0 = acc[mi][ni][0] + bias[col];
                float v1 = acc[mi][ni][1] + bias[col];
                float v2 = acc[mi][ni][2] + bias[col];
                float v3 = acc[mi][ni][3] + bias[col];
                splitf16(v0, vh.x, vl.x);
                splitf16(v1, vh.y, vl.y);
                splitf16(v2, vh.z, vl.z);
                splitf16(v3, vh.w, vl.w);
                *(ushort4*)(Chi + base) = vh;
                *(ushort4*)(Clo + base) = vl;
            }
        }
    } else {
#pragma unroll
        for (int mi = 0; mi < 4; ++mi) {
#pragma unroll
            for (int r = 0; r < 4; ++r) {
                int row = m0 + wm + mi * 16 + l16 * 4 + r;
                int s = row & (S_LEN - 1);
                float tval = 0.f, seval = 0.f;
                if (MODE == 1) { tval = (float)s; seval = seasons[s]; }
#pragma unroll
                for (int ni = 0; ni < 2; ++ni) {
                    int col = n0 + wn + ni * 16 + l15;
                    float v = acc[mi][ni][r] + bias[col];
                    if (MODE == 1) v += tval * rowT[col] + seval * rowS[col];
                    if (MODE == 2) v += pos[(size_t)s * 1024 + col] + seas24[(s % 24) * 256 + (col & 255)];
                    if (MODE == 1 || MODE == 3) v = fmaxf(v, 0.f);
                    size_t o = (size_t)row * 1024 + col;
                    if (EMITF) Cf[o] = v;
                    if (EMITS) {
                        unsigned short hu, lu;
                        splitf16(v * escale, hu, lu);
                        Chi[o] = hu; Clo[o] = lu;
                    }
                }
            }
        }
    }
}

// ---------------------------------------------------------------- MFMA attention + fused output zero-fill
// grid (S/64, B*NH) = 512 blocks, block 256 = 4 waves; wave owns 16 q-rows; KVB=32.
// Fused fill: each block zeroes 786432 B of fill_out (3 nontemporal float4
// stores per thread per KV-iter; 512 blocks x 64 iters covers 2*NEC exactly).
__global__ __launch_bounds__(256, 2) void attn_mfma_k(
    const unsigned short* __restrict__ qhi, const unsigned short* __restrict__ qlo,
    const unsigned short* __restrict__ khi, const unsigned short* __restrict__ klo,
    const unsigned short* __restrict__ vthi, const unsigned short* __restrict__ vtlo,
    unsigned short* __restrict__ ctx_hi, unsigned short* __restrict__ ctx_lo,
    float* __restrict__ fill_out) {
    __shared__ unsigned short Ks_hi[32 * 128];
    __shared__ unsigned short Ks_lo[32 * 128];
    __shared__ unsigned short Vs_hi[128 * 32];
    __shared__ unsigned short Vs_lo[128 * 32];
    __shared__ unsigned int   Ps[64 * 32];

    int bh = blockIdx.y;
    int b = bh >> 3, h = bh & 7;
    int q0 = blockIdx.x * 64;
    int tid = threadIdx.x;
    int lane = tid & 63, w = tid >> 6;
    int l15 = lane & 15, l16 = lane >> 4;
    int wm = w * 16;

    // fused-fill base (float4 units): 512 blocks x 49152 f4 = 2*NEC floats
    int bid = blockIdx.y * 32 + blockIdx.x;
    size_t f4base = (size_t)bid * 49152 + tid;
    v4f zero4 = {0.f, 0.f, 0.f, 0.f};
    v4f* __restrict__ fo = (v4f*)fill_out;

    // Q fragments in registers (A-layout: row=l15, k-chunk=l16)
    v8h qa_h[4], qa_l[4];
    {
        size_t qrow = (size_t)(b * S_LEN + q0 + wm + l15) * H_DIM + h * HDHD;
#pragma unroll
        for (int ks = 0; ks < 4; ++ks) {
            qa_h[ks] = *(const v8h*)(qhi + qrow + ks * 32 + l16 * 8);
            qa_l[ks] = *(const v8h*)(qlo + qrow + ks * 32 + l16 * 8);
        }
    }

    int ktok1 = tid >> 4, kslot1 = tid & 15;
    int ktok2 = ktok1 + 16;
    size_t ksrc1 = (size_t)(b * S_LEN + ktok1) * H_DIM + h * HDHD + ((kslot1 ^ (ktok1 & 7)) * 8);
    size_t ksrc2 = (size_t)(b * S_LEN + ktok2) * H_DIM + h * HDHD + ((kslot1 ^ (ktok2 & 7)) * 8);
    int vd1 = tid >> 2, vslot1 = tid & 3;
    int vd2 = vd1 + 64;
    size_t vsrc1 = (size_t)(bh * HDHD + vd1) * S_LEN + ((vslot1 ^ ((vd1 >> 1) & 3)) * 8);
    size_t vsrc2 = (size_t)(bh * HDHD + vd2) * S_LEN + ((vslot1 ^ ((vd2 >> 1) & 3)) * 8);

    v4f accO[8] = {};
    float mreg[4] = {-1e30f, -1e30f, -1e30f, -1e30f};
    float lreg[4] = {};

    for (int it = 0; it < 64; ++it) {
        int kt = it * 32;
        __syncthreads();
        size_t koff = (size_t)kt * H_DIM;
        gld_lds16(khi + ksrc1 + koff, &Ks_hi[tid * 8]);
        gld_lds16(khi + ksrc2 + koff, &Ks_hi[(tid + 256) * 8]);
        gld_lds16(klo + ksrc1 + koff, &Ks_lo[tid * 8]);
        gld_lds16(klo + ksrc2 + koff, &Ks_lo[(tid + 256) * 8]);
        gld_lds16(vthi + vsrc1 + kt, &Vs_hi[tid * 8]);
        gld_lds16(vthi + vsrc2 + kt, &Vs_hi[(tid + 256) * 8]);
        gld_lds16(vtlo + vsrc1 + kt, &Vs_lo[tid * 8]);
        gld_lds16(vtlo + vsrc2 + kt, &Vs_lo[(tid + 256) * 8]);
        // fused zero-fill: 3 nontemporal float4 stores/thread/iter
        __builtin_nontemporal_store(zero4, fo + f4base + (size_t)(it * 3 + 0) * 256);
        __builtin_nontemporal_store(zero4, fo + f4base + (size_t)(it * 3 + 1) * 256);
        __builtin_nontemporal_store(zero4, fo + f4base + (size_t)(it * 3 + 2) * 256);
        __syncthreads();

        // ---- QK^T: S[16 q][32 tok]
        v4f s0 = {}, s1 = {};
#pragma unroll
        for (int ks = 0; ks < 4; ++ks) {
#pragma unroll
            for (int nt = 0; nt < 2; ++nt) {
                int tok = nt * 16 + l15;
                int slot = (ks * 4 + l16) ^ (tok & 7);
                v8h bhf = *(const v8h*)&Ks_hi[tok * 128 + slot * 8];
                v8h blf = *(const v8h*)&Ks_lo[tok * 128 + slot * 8];
                v4f& ss = nt ? s1 : s0;
                ss = __builtin_amdgcn_mfma_f32_16x16x32_f16(qa_h[ks], bhf, ss, 0, 0, 0);
                ss = __builtin_amdgcn_mfma_f32_16x16x32_f16(qa_l[ks], bhf, ss, 0, 0, 0);
                ss = __builtin_amdgcn_mfma_f32_16x16x32_f16(qa_h[ks], blf, ss, 0, 0, 0);
            }
        }

        // ---- online softmax
        float p0[4], p1[4], alpha[4];
#pragma unroll
        for (int r = 0; r < 4; ++r) {
            float tmax = fmaxf(s0[r], s1[r]);
            tmax = fmaxf(tmax, __shfl_xor(tmax, 1));
            tmax = fmaxf(tmax, __shfl_xor(tmax, 2));
            tmax = fmaxf(tmax, __shfl_xor(tmax, 4));
            tmax = fmaxf(tmax, __shfl_xor(tmax, 8));
            float mnew = fmaxf(mreg[r], tmax);
            alpha[r] = __expf(mreg[r] - mnew);
            p0[r] = __expf(s0[r] - mnew);
            p1[r] = __expf(s1[r] - mnew);
            float lt = p0[r] + p1[r];
            lt += __shfl_xor(lt, 1);
            lt += __shfl_xor(lt, 2);
            lt += __shfl_xor(lt, 4);
            lt += __shfl_xor(lt, 8);
            lreg[r] = lreg[r] * alpha[r] + lt;
            mreg[r] = mnew;
        }
#pragma unroll
        for (int nt = 0; nt < 8; ++nt)
#pragma unroll
            for (int r = 0; r < 4; ++r) accO[nt][r] *= alpha[r];

        // ---- P -> LDS packed u32 (hi | lo<<16), swizzled
#pragma unroll
        for (int r = 0; r < 4; ++r) {
            int qq = wm + l16 * 4 + r;
            unsigned short ph, pl;
            splitf16(p0[r], ph, pl);
            int k0i = l15;
            Ps[qq * 32 + ((((k0i >> 2) ^ (qq & 7)) << 2) | (k0i & 3))] =
                (unsigned)ph | ((unsigned)pl << 16);
            splitf16(p1[r], ph, pl);
            int k1i = 16 + l15;
            Ps[qq * 32 + ((((k1i >> 2) ^ (qq & 7)) << 2) | (k1i & 3))] =
                (unsigned)ph | ((unsigned)pl << 16);
        }
        __syncthreads();

        // ---- PV
        int qq = wm + l15;
        int sA = (l16 * 2) ^ (qq & 7);
        int sB = (l16 * 2 + 1) ^ (qq & 7);
        uint4 ua = *(const uint4*)&Ps[qq * 32 + sA * 4];
        uint4 ub = *(const uint4*)&Ps[qq * 32 + sB * 4];
        uint4 ahw, alw;
        ahw.x = (ua.x & 0xffffu) | (ua.y << 16);
        ahw.y = (ua.z & 0xffffu) | (ua.w << 16);
        ahw.z = (ub.x & 0xffffu) | (ub.y << 16);
        ahw.w = (ub.z & 0xffffu) | (ub.w << 16);
        alw.x = (ua.x >> 16) | (ua.y & 0xffff0000u);
        alw.y = (ua.z >> 16) | (ua.w & 0xffff0000u);
        alw.z = (ub.x >> 16) | (ub.y & 0xffff0000u);
        alw.w = (ub.z >> 16) | (ub.w & 0xffff0000u);
        v8h pA_h = __builtin_bit_cast(v8h, ahw);
        v8h pA_l = __builtin_bit_cast(v8h, alw);
#pragma unroll
        for (int nt = 0; nt < 8; ++nt) {
            int d = nt * 16 + l15;
            int slot = l16 ^ ((d >> 1) & 3);
            v8h vhf = *(const v8h*)&Vs_hi[d * 32 + slot * 8];
            v8h vlf = *(const v8h*)&Vs_lo[d * 32 + slot * 8];
            accO[nt] = __builtin_amdgcn_mfma_f32_16x16x32_f16(pA_h, vhf, accO[nt], 0, 0, 0);
            accO[nt] = __builtin_amdgcn_mfma_f32_16x16x32_f16(pA_l, vhf, accO[nt], 0, 0, 0);
            accO[nt] = __builtin_amdgcn_mfma_f32_16x16x32_f16(pA_h, vlf, accO[nt], 0, 0, 0);
        }
        __syncthreads();
    }

    // ---- epilogue: split ctx out
    float linv[4];
#pragma unroll
    for (int r = 0; r < 4; ++r) linv[r] = 1.f / lreg[r];
#pragma unroll
    for (int nt = 0; nt < 8; ++nt) {
#pragma unroll
        for (int r = 0; r < 4; ++r) {
            size_t o = (size_t)(b * S_LEN + q0 + wm + l16 * 4 + r) * H_DIM + h * HDHD + nt * 16 + l15;
            unsigned short hu, lu;
            splitf16(accO[nt][r] * linv[r], hu, lu);
            ctx_hi[o] = hu;
            ctx_lo[o] = lu;
        }
    }
}

// ---------------------------------------------------------------- router logits
__global__ void logits_k(const float* __restrict__ h1, const float* __restrict__ Wr2,
                         const float* __restrict__ br2, float* __restrict__ logits) {
    int tid = threadIdx.x;
    int tok = blockIdx.x * 32 + (tid >> 3);
    int e = tid & 7;
    const float* hrow = h1 + (size_t)tok * 1024;
    float acc = br2[e];
    for (int i = 0; i < 1024; ++i) acc = fmaf(hrow[i], Wr2[i * 8 + e], acc);
    logits[(size_t)tok * 8 + e] = acc;
}

// ---------------------------------------------------------------- softmax + top2 + scatter
__global__ void topk_k(const float* __restrict__ logits, float* __restrict__ out) {
    int tok = blockIdx.x * 256 + threadIdx.x;
    if (tok >= N_TOK) return;
    float l[8], p[8];
    float mx = -1e30f;
#pragma unroll
    for (int e = 0; e < 8; ++e) { l[e] = logits[(size_t)tok * 8 + e]; mx = fmaxf(mx, l[e]); }
    float sum = 0.f;
#pragma unroll
    for (int e = 0; e < 8; ++e) { p[e] = __expf(l[e] - mx); sum += p[e]; }
    float inv = 1.f / sum;
#pragma unroll
    for (int e = 0; e < 8; ++e) p[e] *= inv;
    const size_t NEC = (size_t)N_TOK * E_EXP * CAPV;
    float* probs_out = out + 2 * NEC;
#pragma unroll
    for (int e = 0; e < 8; ++e) probs_out[(size_t)tok * 8 + e] = p[e];
    int i1 = 0;
#pragma unroll
    for (int e = 1; e < 8; ++e) if (p[e] > p[i1]) i1 = e;
    int i2 = -1;
#pragma unroll
    for (int e = 0; e < 8; ++e) {
        if (e == i1) continue;
        if (i2 < 0 || p[e] > p[i2]) i2 = e;
    }
    float v1 = p[i1], v2 = p[i2], tv = v1 + v2;
    size_t base = (size_t)tok * E_EXP * CAPV;
    out[base + (size_t)i1 * CAPV] = 1.f;
    out[base + (size_t)i2 * CAPV] = 1.f;
    out[NEC + base + (size_t)i1 * CAPV] = v1 / tv;
    out[NEC + base + (size_t)i2 * CAPV] = v2 / tv;
}

// ---------------------------------------------------------------- aux loss
__global__ void aux_k(const float* __restrict__ probs, float* __restrict__ out_aux) {
    __shared__ float part[256];
    int tid = threadIdx.x;
    int e = tid & 7, chunk = tid >> 3;
    float s = 0.f;
    for (int t = chunk * 128; t < (chunk + 1) * 128; ++t)
        s += probs[(size_t)t * 8 + e];
    part[tid] = s;
    __syncthreads();
    if (tid < 8) {
        float tot = 0.f;
        for (int c = 0; c < 32; ++c) tot += part[c * 8 + e];
        part[tid] = tot / (float)N_TOK;
    }
    __syncthreads();
    if (tid == 0) {
        float aux = 0.f;
        for (int e2 = 0; e2 < 8; ++e2) {
            float pm = part[e2];
            aux += pm * logf(pm * 8.f + 1e-9f);
        }
        *out_aux = aux;
    }
}

// ---------------------------------------------------------------- launch
extern "C" void kernel_launch(void* const* d_in, const int* in_sizes, int n_in,
                              void* d_out, int out_size, void* d_ws, size_t ws_size,
                              hipStream_t stream) {
    const float* hid = (const float*)d_in[0];
    const float* pos = (const float*)d_in[1];
    const float* We1 = (const float*)d_in[2];
    const float* be1 = (const float*)d_in[3];
    const float* We2 = (const float*)d_in[4];
    const float* be2 = (const float*)d_in[5];
    const float* Ws1 = (const float*)d_in[6];
    const float* bs1 = (const float*)d_in[7];
    const float* Ws2 = (const float*)d_in[8];
    const float* bs2 = (const float*)d_in[9];
    const float* Wq  = (const float*)d_in[10]; const float* bq = (const float*)d_in[11];
    const float* Wk  = (const float*)d_in[12]; const float* bk = (const float*)d_in[13];
    const float* Wv  = (const float*)d_in[14]; const float* bv = (const float*)d_in[15];
    const float* Wo  = (const float*)d_in[16]; const float* bo = (const float*)d_in[17];
    const float* Wr1 = (const float*)d_in[18]; const float* br1 = (const float*)d_in[19];
    const float* Wr2 = (const float*)d_in[20]; const float* br2 = (const float*)d_in[21];

    float* out = (float*)d_out;
    char* base = (char*)d_ws;
    const size_t AC  = (size_t)N_TOK * H_DIM;
    const size_t SPC = AC * 2;
    const size_t FB  = AC * 4;
    unsigned short* B1hi = (unsigned short*)(base);
    unsigned short* B1lo = (unsigned short*)(base + SPC);
    unsigned short* B2hi = (unsigned short*)(base + FB);
    unsigned short* B2lo = (unsigned short*)(base + FB + SPC);
    unsigned short* Qhi  = (unsigned short*)(base + 2 * FB);
    unsigned short* Qlo  = (unsigned short*)(base + 2 * FB + SPC);
    unsigned short* Khi  = (unsigned short*)(base + 3 * FB);
    unsigned short* Klo  = (unsigned short*)(base + 3 * FB + SPC);
    unsigned short* VThi = (unsigned short*)(base + 4 * FB);
    unsigned short* VTlo = (unsigned short*)(base + 4 * FB + SPC);
    unsigned short* Whi  = (unsigned short*)(base + 5 * FB);
    unsigned short* Wlo  = (unsigned short*)(base + 5 * FB + (size_t)1024 * 1024 * 2);
    float* h1f     = (float*)(base + 3 * FB);
    float* seas24  = (float*)(base + 5 * FB + (size_t)1024 * 1024 * 4);
    float* seasons = seas24 + 6144;
    float* logits  = seasons + 2048;

    const size_t NEC = (size_t)N_TOK * E_EXP * CAPV;
    const float QSCALE = 0.08838834764831845f;

    season_k<<<8, 256, 0, stream>>>(seasons);
    seas24_k<<<24, 256, 0, stream>>>(seasons, Ws1, bs1, Ws2, bs2, seas24);
    convert_split_k<<<4096, 256, 0, stream>>>(hid, B1hi, B1lo, (int)(AC / 4));

    dim3 gg(16, 32), blk(256);
    dim3 wg(16, 16);

    wconv_t_k<<<wg, blk, 0, stream>>>(We1, Whi, Wlo);
    gemm_split<1, 0, 1, 0><<<gg, blk, 0, stream>>>(B1hi, B1lo, Whi, Wlo, be1,
        nullptr, B2hi, B2lo,
        We1 + (size_t)1024 * 1024, We1 + (size_t)1025 * 1024, seasons, nullptr, nullptr, 1.f);
    wconv_t_k<<<wg, blk, 0, stream>>>(We2, Whi, Wlo);
    gemm_split<2, 0, 1, 0><<<gg, blk, 0, stream>>>(B2hi, B2lo, Whi, Wlo, be2,
        nullptr, B1hi, B1lo, nullptr, nullptr, nullptr, pos, seas24, 1.f);
    wconv_t_k<<<wg, blk, 0, stream>>>(Wq, Whi, Wlo);
    gemm_split<0, 0, 1, 0><<<gg, blk, 0, stream>>>(B1hi, B1lo, Whi, Wlo, bq,
        nullptr, Qhi, Qlo, nullptr, nullptr, nullptr, nullptr, nullptr, QSCALE);
    wconv_t_k<<<wg, blk, 0, stream>>>(Wk, Whi, Wlo);
    gemm_split<0, 0, 1, 0><<<gg, blk, 0, stream>>>(B1hi, B1lo, Whi, Wlo, bk,
        nullptr, Khi, Klo, nullptr, nullptr, nullptr, nullptr, nullptr, 1.f);
    wconv_t_k<<<wg, blk, 0, stream>>>(Wv, Whi, Wlo);
    gemm_split<0, 0, 0, 1><<<gg, blk, 0, stream>>>(B1hi, B1lo, Whi, Wlo, bv,
        nullptr, VThi, VTlo, nullptr, nullptr, nullptr, nullptr, nullptr, 1.f);

    attn_mfma_k<<<dim3(32, 16), 256, 0, stream>>>(Qhi, Qlo, Khi, Klo, VThi, VTlo,
                                                  B2hi, B2lo, out);

    wconv_t_k<<<wg, blk, 0, stream>>>(Wo, Whi, Wlo);
    gemm_split<0, 0, 1, 0><<<gg, blk, 0, stream>>>(B2hi, B2lo, Whi, Wlo, bo,
        nullptr, B1hi, B1lo, nullptr, nullptr, nullptr, nullptr, nullptr, 1.f);
    wconv_t_k<<<wg, blk, 0, stream>>>(Wr1, Whi, Wlo);
    gemm_split<3, 1, 0, 0><<<gg, blk, 0, stream>>>(B1hi, B1lo, Whi, Wlo, br1,
        h1f, nullptr, nullptr, nullptr, nullptr, nullptr, nullptr, nullptr, 1.f);

    logits_k<<<128, 256, 0, stream>>>(h1f, Wr2, br2, logits);
    topk_k<<<16, 256, 0, stream>>>(logits, out);
    aux_k<<<1, 256, 0, stream>>>(out + 2 * NEC, out + 2 * NEC + (size_t)N_TOK * E_EXP);
}

// Round 6
// 628.972 us; speedup vs baseline: 3.6123x; 1.0700x over previous
//
#include <hip/hip_runtime.h>
#include <hip/hip_fp16.h>
#include <math.h>

#define N_TOK 4096
#define S_LEN 2048
#define H_DIM 1024
#define E_EXP 8
#define CAPV  1536
#define NHEAD 8
#define HDHD  128

typedef __attribute__((ext_vector_type(8))) _Float16 v8h;
typedef __attribute__((ext_vector_type(4))) float v4f;

__device__ __forceinline__ void splitf16(float v, unsigned short& h, unsigned short& l) {
    __half hh = __float2half(v);
    h = __half_as_ushort(hh);
    l = __half_as_ushort(__float2half(v - __half2float(hh)));
}

__device__ __forceinline__ void gld_lds16(const void* g, void* l) {
    __builtin_amdgcn_global_load_lds(
        (const __attribute__((address_space(1))) unsigned int*)g,
        (__attribute__((address_space(3))) unsigned int*)l,
        16, 0, 0);
}

// ---------------------------------------------------------------- seasons
__global__ void season_k(float* seasons) {
    int s = blockIdx.x * 256 + threadIdx.x;
    if (s < S_LEN) {
        double a = (double)s * 2.0 * M_PI / 24.0;
        seasons[s] = (float)sin(a);
    }
}

__global__ void seas24_k(const float* __restrict__ seasons,
                         const float* __restrict__ Ws1, const float* __restrict__ bs1,
                         const float* __restrict__ Ws2, const float* __restrict__ bs2,
                         float* __restrict__ seas24) {
    __shared__ float hbuf[256];
    int m = blockIdx.x;
    float sv = seasons[m];
    int j = threadIdx.x;
    hbuf[j] = fmaxf(sv * Ws1[j] + bs1[j], 0.f);
    __syncthreads();
    float acc = bs2[j];
    for (int i = 0; i < 256; ++i) acc = fmaf(hbuf[i], Ws2[i * 256 + j], acc);
    seas24[m * 256 + j] = acc;
}

// ---------------------------------------------------------------- f32 -> f16 hi/lo split
__global__ void convert_split_k(const float* __restrict__ in,
                                unsigned short* __restrict__ hi,
                                unsigned short* __restrict__ lo, int n4) {
    int i = blockIdx.x * 256 + threadIdx.x;
    if (i >= n4) return;
    float4 v = ((const float4*)in)[i];
    ushort4 h, l;
    splitf16(v.x, h.x, l.x);
    splitf16(v.y, h.y, l.y);
    splitf16(v.z, h.z, l.z);
    splitf16(v.w, h.w, l.w);
    ((ushort4*)hi)[i] = h;
    ((ushort4*)lo)[i] = l;
}

// ---------------------------------------------------------------- W[1024][1024] -> W^T hi/lo f16
__global__ __launch_bounds__(256) void wconv_t_k(const float* __restrict__ W,
                                                 unsigned short* __restrict__ Thi,
                                                 unsigned short* __restrict__ Tlo) {
    __shared__ unsigned short Hs[64][65];
    __shared__ unsigned short Ls[64][65];
    int k0 = blockIdx.y * 64, n0 = blockIdx.x * 64;
    int tid = threadIdx.x;
#pragma unroll
    for (int i = 0; i < 4; ++i) {
        int idx = tid + i * 256;
        int kk = idx >> 4, n4 = idx & 15;
        float4 v = *(const float4*)(W + (size_t)(k0 + kk) * 1024 + n0 + n4 * 4);
        unsigned short h, l;
        splitf16(v.x, h, l); Hs[n4 * 4 + 0][kk] = h; Ls[n4 * 4 + 0][kk] = l;
        splitf16(v.y, h, l); Hs[n4 * 4 + 1][kk] = h; Ls[n4 * 4 + 1][kk] = l;
        splitf16(v.z, h, l); Hs[n4 * 4 + 2][kk] = h; Ls[n4 * 4 + 2][kk] = l;
        splitf16(v.w, h, l); Hs[n4 * 4 + 3][kk] = h; Ls[n4 * 4 + 3][kk] = l;
    }
    __syncthreads();
#pragma unroll
    for (int i = 0; i < 4; ++i) {
        int idx = tid + i * 256;
        int n = idx >> 4, k4 = idx & 15;
        ushort4 h = make_ushort4(Hs[n][k4 * 4], Hs[n][k4 * 4 + 1], Hs[n][k4 * 4 + 2], Hs[n][k4 * 4 + 3]);
        ushort4 l = make_ushort4(Ls[n][k4 * 4], Ls[n][k4 * 4 + 1], Ls[n][k4 * 4 + 2], Ls[n][k4 * 4 + 3]);
        *(ushort4*)(Thi + (size_t)(n0 + n) * 1024 + k0 + k4 * 4) = h;
        *(ushort4*)(Tlo + (size_t)(n0 + n) * 1024 + k0 + k4 * 4) = l;
    }
}

// ---------------------------------------------------------------- split-f16 MFMA GEMM (single-pass)
// Per K-step: stage Ah,Al (128x32 each), Wh,Wl (64x32 each); 24 MFMA/wave.
template <int MODE, int EMITF, int EMITS, int EMITT>
__global__ __launch_bounds__(256, 2) void gemm_split(
    const unsigned short* __restrict__ Ahi, const unsigned short* __restrict__ Alo,
    const unsigned short* __restrict__ WThi, const unsigned short* __restrict__ WTlo,
    const float* __restrict__ bias, float* __restrict__ Cf,
    unsigned short* __restrict__ Chi, unsigned short* __restrict__ Clo,
    const float* __restrict__ rowT, const float* __restrict__ rowS,
    const float* __restrict__ seasons, const float* __restrict__ pos,
    const float* __restrict__ seas24, float escale) {
    __shared__ unsigned short Ash[128 * 32];
    __shared__ unsigned short Asl[128 * 32];
    __shared__ unsigned short Bsh[64 * 32];
    __shared__ unsigned short Bsl[64 * 32];
    int tid = threadIdx.x;
    int lane = tid & 63, w = tid >> 6;
    int l15 = lane & 15, l16 = lane >> 4;
    int wm = (w >> 1) * 64, wn = (w & 1) * 32;
    int m0 = blockIdx.y * 128, n0 = blockIdx.x * 64;

    int ac0 = w * 128 + lane;
    int ac1 = ac0 + 64;
    int bc  = w * 64 + lane;
    int ar0 = ac0 >> 2, ar1 = ac1 >> 2, bn = bc >> 2;
    size_t a_src0 = (size_t)(m0 + ar0) * 1024 + (((ac0 & 3) ^ (ar0 & 3)) * 8);
    size_t a_src1 = (size_t)(m0 + ar1) * 1024 + (((ac1 & 3) ^ (ar1 & 3)) * 8);
    size_t b_src  = (size_t)(n0 + bn) * 1024 + (((bc & 3) ^ (bn & 3)) * 8);
    unsigned short* ah_lds0 = &Ash[ac0 * 8];
    unsigned short* ah_lds1 = &Ash[ac1 * 8];
    unsigned short* al_lds0 = &Asl[ac0 * 8];
    unsigned short* al_lds1 = &Asl[ac1 * 8];
    unsigned short* bh_lds  = &Bsh[bc * 8];
    unsigned short* bl_lds  = &Bsl[bc * 8];

    int a_off[4], b_off[2];
#pragma unroll
    for (int mi = 0; mi < 4; ++mi) {
        int row = wm + mi * 16 + l15;
        a_off[mi] = row * 32 + ((l16 ^ (row & 3)) * 8);
    }
#pragma unroll
    for (int ni = 0; ni < 2; ++ni) {
        int n = wn + ni * 16 + l15;
        b_off[ni] = n * 32 + ((l16 ^ (n & 3)) * 8);
    }

    v4f acc[4][2] = {};

    for (int k0 = 0; k0 < 1024; k0 += 32) {
        __syncthreads();
        gld_lds16(Ahi + a_src0 + k0, ah_lds0);
        gld_lds16(Ahi + a_src1 + k0, ah_lds1);
        gld_lds16(Alo + a_src0 + k0, al_lds0);
        gld_lds16(Alo + a_src1 + k0, al_lds1);
        gld_lds16(WThi + b_src + k0, bh_lds);
        gld_lds16(WTlo + b_src + k0, bl_lds);
        __syncthreads();
        v8h ah[4], al[4], bh[2], bl[2];
#pragma unroll
        for (int mi = 0; mi < 4; ++mi) {
            ah[mi] = *(const v8h*)&Ash[a_off[mi]];
            al[mi] = *(const v8h*)&Asl[a_off[mi]];
        }
#pragma unroll
        for (int ni = 0; ni < 2; ++ni) {
            bh[ni] = *(const v8h*)&Bsh[b_off[ni]];
            bl[ni] = *(const v8h*)&Bsl[b_off[ni]];
        }
#pragma unroll
        for (int mi = 0; mi < 4; ++mi)
#pragma unroll
            for (int ni = 0; ni < 2; ++ni) {
                acc[mi][ni] = __builtin_amdgcn_mfma_f32_16x16x32_f16(ah[mi], bh[ni], acc[mi][ni], 0, 0, 0);
                acc[mi][ni] = __builtin_amdgcn_mfma_f32_16x16x32_f16(al[mi], bh[ni], acc[mi][ni], 0, 0, 0);
                acc[mi][ni] = __builtin_amdgcn_mfma_f32_16x16x32_f16(ah[mi], bl[ni], acc[mi][ni], 0, 0, 0);
            }
    }

    if (EMITT) {
#pragma unroll
        for (int mi = 0; mi < 4; ++mi) {
            int row0 = m0 + wm + mi * 16 + l16 * 4;
            int bb = row0 >> 11, ss = row0 & 2047;
#pragma unroll
            for (int ni = 0; ni < 2; ++ni) {
                int col = n0 + wn + ni * 16 + l15;
                int hh = col >> 7, dd = col & 127;
                size_t base = ((size_t)((bb * 8 + hh) * 128 + dd)) * 2048 + ss;
                ushort4 vh, vl;
                float v0 = acc[mi][ni][0] + bias[col];
                float v1 = acc[mi][ni][1] + bias[col];
                float v2 = acc[mi][ni][2] + bias[col];
                float v3 = acc[mi][ni][3] + bias[col];
                splitf16(v0, vh.x, vl.x);
                splitf16(v1, vh.y, vl.y);
                splitf16(v2, vh.z, vl.z);
                splitf16(v3, vh.w, vl.w);
                *(ushort4*)(Chi + base) = vh;
                *(ushort4*)(Clo + base) = vl;
            }
        }
    } else {
#pragma unroll
        for (int mi = 0; mi < 4; ++mi) {
#pragma unroll
            for (int r = 0; r < 4; ++r) {
                int row = m0 + wm + mi * 16 + l16 * 4 + r;
                int s = row & (S_LEN - 1);
                float tval = 0.f, seval = 0.f;
                if (MODE == 1) { tval = (float)s; seval = seasons[s]; }
#pragma unroll
                for (int ni = 0; ni < 2; ++ni) {
                    int col = n0 + wn + ni * 16 + l15;
                    float v = acc[mi][ni][r] + bias[col];
                    if (MODE == 1) v += tval * rowT[col] + seval * rowS[col];
                    if (MODE == 2) v += pos[(size_t)s * 1024 + col] + seas24[(s % 24) * 256 + (col & 255)];
                    if (MODE == 1 || MODE == 3) v = fmaxf(v, 0.f);
                    size_t o = (size_t)row * 1024 + col;
                    if (EMITF) Cf[o] = v;
                    if (EMITS) {
                        unsigned short hu, lu;
                        splitf16(v * escale, hu, lu);
                        Chi[o] = hu; Clo[o] = lu;
                    }
                }
            }
        }
    }
}

// ---------------------------------------------------------------- MFMA attention
__global__ __launch_bounds__(256, 2) void attn_mfma_k(
    const unsigned short* __restrict__ qhi, const unsigned short* __restrict__ qlo,
    const unsigned short* __restrict__ khi, const unsigned short* __restrict__ klo,
    const unsigned short* __restrict__ vthi, const unsigned short* __restrict__ vtlo,
    unsigned short* __restrict__ ctx_hi, unsigned short* __restrict__ ctx_lo) {
    __shared__ unsigned short Ks_hi[32 * 128];
    __shared__ unsigned short Ks_lo[32 * 128];
    __shared__ unsigned short Vs_hi[128 * 32];
    __shared__ unsigned short Vs_lo[128 * 32];
    __shared__ unsigned int   Ps[64 * 32];

    int bh = blockIdx.y;
    int b = bh >> 3, h = bh & 7;
    int q0 = blockIdx.x * 64;
    int tid = threadIdx.x;
    int lane = tid & 63, w = tid >> 6;
    int l15 = lane & 15, l16 = lane >> 4;
    int wm = w * 16;

    v8h qa_h[4], qa_l[4];
    {
        size_t qrow = (size_t)(b * S_LEN + q0 + wm + l15) * H_DIM + h * HDHD;
#pragma unroll
        for (int ks = 0; ks < 4; ++ks) {
            qa_h[ks] = *(const v8h*)(qhi + qrow + ks * 32 + l16 * 8);
            qa_l[ks] = *(const v8h*)(qlo + qrow + ks * 32 + l16 * 8);
        }
    }

    int ktok1 = tid >> 4, kslot1 = tid & 15;
    int ktok2 = ktok1 + 16;
    size_t ksrc1 = (size_t)(b * S_LEN + ktok1) * H_DIM + h * HDHD + ((kslot1 ^ (ktok1 & 7)) * 8);
    size_t ksrc2 = (size_t)(b * S_LEN + ktok2) * H_DIM + h * HDHD + ((kslot1 ^ (ktok2 & 7)) * 8);
    int vd1 = tid >> 2, vslot1 = tid & 3;
    int vd2 = vd1 + 64;
    size_t vsrc1 = (size_t)(bh * HDHD + vd1) * S_LEN + ((vslot1 ^ ((vd1 >> 1) & 3)) * 8);
    size_t vsrc2 = (size_t)(bh * HDHD + vd2) * S_LEN + ((vslot1 ^ ((vd2 >> 1) & 3)) * 8);

    v4f accO[8] = {};
    float mreg[4] = {-1e30f, -1e30f, -1e30f, -1e30f};
    float lreg[4] = {};

    for (int kt = 0; kt < S_LEN; kt += 32) {
        __syncthreads();
        size_t koff = (size_t)kt * H_DIM;
        gld_lds16(khi + ksrc1 + koff, &Ks_hi[tid * 8]);
        gld_lds16(khi + ksrc2 + koff, &Ks_hi[(tid + 256) * 8]);
        gld_lds16(klo + ksrc1 + koff, &Ks_lo[tid * 8]);
        gld_lds16(klo + ksrc2 + koff, &Ks_lo[(tid + 256) * 8]);
        gld_lds16(vthi + vsrc1 + kt, &Vs_hi[tid * 8]);
        gld_lds16(vthi + vsrc2 + kt, &Vs_hi[(tid + 256) * 8]);
        gld_lds16(vtlo + vsrc1 + kt, &Vs_lo[tid * 8]);
        gld_lds16(vtlo + vsrc2 + kt, &Vs_lo[(tid + 256) * 8]);
        __syncthreads();

        v4f s0 = {}, s1 = {};
#pragma unroll
        for (int ks = 0; ks < 4; ++ks) {
#pragma unroll
            for (int nt = 0; nt < 2; ++nt) {
                int tok = nt * 16 + l15;
                int slot = (ks * 4 + l16) ^ (tok & 7);
                v8h bhf = *(const v8h*)&Ks_hi[tok * 128 + slot * 8];
                v8h blf = *(const v8h*)&Ks_lo[tok * 128 + slot * 8];
                v4f& ss = nt ? s1 : s0;
                ss = __builtin_amdgcn_mfma_f32_16x16x32_f16(qa_h[ks], bhf, ss, 0, 0, 0);
                ss = __builtin_amdgcn_mfma_f32_16x16x32_f16(qa_l[ks], bhf, ss, 0, 0, 0);
                ss = __builtin_amdgcn_mfma_f32_16x16x32_f16(qa_h[ks], blf, ss, 0, 0, 0);
            }
        }

        float p0[4], p1[4], alpha[4];
#pragma unroll
        for (int r = 0; r < 4; ++r) {
            float tmax = fmaxf(s0[r], s1[r]);
            tmax = fmaxf(tmax, __shfl_xor(tmax, 1));
            tmax = fmaxf(tmax, __shfl_xor(tmax, 2));
            tmax = fmaxf(tmax, __shfl_xor(tmax, 4));
            tmax = fmaxf(tmax, __shfl_xor(tmax, 8));
            float mnew = fmaxf(mreg[r], tmax);
            alpha[r] = __expf(mreg[r] - mnew);
            p0[r] = __expf(s0[r] - mnew);
            p1[r] = __expf(s1[r] - mnew);
            float lt = p0[r] + p1[r];
            lt += __shfl_xor(lt, 1);
            lt += __shfl_xor(lt, 2);
            lt += __shfl_xor(lt, 4);
            lt += __shfl_xor(lt, 8);
            lreg[r] = lreg[r] * alpha[r] + lt;
            mreg[r] = mnew;
        }
#pragma unroll
        for (int nt = 0; nt < 8; ++nt)
#pragma unroll
            for (int r = 0; r < 4; ++r) accO[nt][r] *= alpha[r];

#pragma unroll
        for (int r = 0; r < 4; ++r) {
            int qq = wm + l16 * 4 + r;
            unsigned short ph, pl;
            splitf16(p0[r], ph, pl);
            int k0i = l15;
            Ps[qq * 32 + ((((k0i >> 2) ^ (qq & 7)) << 2) | (k0i & 3))] =
                (unsigned)ph | ((unsigned)pl << 16);
            splitf16(p1[r], ph, pl);
            int k1i = 16 + l15;
            Ps[qq * 32 + ((((k1i >> 2) ^ (qq & 7)) << 2) | (k1i & 3))] =
                (unsigned)ph | ((unsigned)pl << 16);
        }
        __syncthreads();

        int qq = wm + l15;
        int sA = (l16 * 2) ^ (qq & 7);
        int sB = (l16 * 2 + 1) ^ (qq & 7);
        uint4 ua = *(const uint4*)&Ps[qq * 32 + sA * 4];
        uint4 ub = *(const uint4*)&Ps[qq * 32 + sB * 4];
        uint4 ahw, alw;
        ahw.x = (ua.x & 0xffffu) | (ua.y << 16);
        ahw.y = (ua.z & 0xffffu) | (ua.w << 16);
        ahw.z = (ub.x & 0xffffu) | (ub.y << 16);
        ahw.w = (ub.z & 0xffffu) | (ub.w << 16);
        alw.x = (ua.x >> 16) | (ua.y & 0xffff0000u);
        alw.y = (ua.z >> 16) | (ua.w & 0xffff0000u);
        alw.z = (ub.x >> 16) | (ub.y & 0xffff0000u);
        alw.w = (ub.z >> 16) | (ub.w & 0xffff0000u);
        v8h pA_h = __builtin_bit_cast(v8h, ahw);
        v8h pA_l = __builtin_bit_cast(v8h, alw);
#pragma unroll
        for (int nt = 0; nt < 8; ++nt) {
            int d = nt * 16 + l15;
            int slot = l16 ^ ((d >> 1) & 3);
            v8h vhf = *(const v8h*)&Vs_hi[d * 32 + slot * 8];
            v8h vlf = *(const v8h*)&Vs_lo[d * 32 + slot * 8];
            accO[nt] = __builtin_amdgcn_mfma_f32_16x16x32_f16(pA_h, vhf, accO[nt], 0, 0, 0);
            accO[nt] = __builtin_amdgcn_mfma_f32_16x16x32_f16(pA_l, vhf, accO[nt], 0, 0, 0);
            accO[nt] = __builtin_amdgcn_mfma_f32_16x16x32_f16(pA_h, vlf, accO[nt], 0, 0, 0);
        }
        __syncthreads();
    }

    float linv[4];
#pragma unroll
    for (int r = 0; r < 4; ++r) linv[r] = 1.f / lreg[r];
#pragma unroll
    for (int nt = 0; nt < 8; ++nt) {
#pragma unroll
        for (int r = 0; r < 4; ++r) {
            size_t o = (size_t)(b * S_LEN + q0 + wm + l16 * 4 + r) * H_DIM + h * HDHD + nt * 16 + l15;
            unsigned short hu, lu;
            splitf16(accO[nt][r] * linv[r], hu, lu);
            ctx_hi[o] = hu;
            ctx_lo[o] = lu;
        }
    }
}

// ---------------------------------------------------------------- router logits
__global__ void logits_k(const float* __restrict__ h1, const float* __restrict__ Wr2,
                         const float* __restrict__ br2, float* __restrict__ logits) {
    int tid = threadIdx.x;
    int tok = blockIdx.x * 32 + (tid >> 3);
    int e = tid & 7;
    const float* hrow = h1 + (size_t)tok * 1024;
    float acc = br2[e];
    for (int i = 0; i < 1024; ++i) acc = fmaf(hrow[i], Wr2[i * 8 + e], acc);
    logits[(size_t)tok * 8 + e] = acc;
}

// ---------------------------------------------------------------- fused softmax+top2+zero-fill writer
// block per token (4096 blocks). Writes the token's full dispatch & combine
// rows (3072 f4 each, mostly zeros) with NT stores + probs.
__global__ __launch_bounds__(256) void topk_fill_k(const float* __restrict__ logits,
                                                   float* __restrict__ out) {
    int tok = blockIdx.x;
    int tid = threadIdx.x;
    float l[8], p[8];
    float mx = -1e30f;
#pragma unroll
    for (int e = 0; e < 8; ++e) { l[e] = logits[(size_t)tok * 8 + e]; mx = fmaxf(mx, l[e]); }
    float sum = 0.f;
#pragma unroll
    for (int e = 0; e < 8; ++e) { p[e] = __expf(l[e] - mx); sum += p[e]; }
    float inv = 1.f / sum;
#pragma unroll
    for (int e = 0; e < 8; ++e) p[e] *= inv;
    int i1 = 0;
#pragma unroll
    for (int e = 1; e < 8; ++e) if (p[e] > p[i1]) i1 = e;
    int i2 = -1;
#pragma unroll
    for (int e = 0; e < 8; ++e) {
        if (e == i1) continue;
        if (i2 < 0 || p[e] > p[i2]) i2 = e;
    }
    float tv = p[i1] + p[i2];
    float w1 = p[i1] / tv, w2 = p[i2] / tv;

    const size_t NEC = (size_t)N_TOK * E_EXP * CAPV;
    v4f* dbase = (v4f*)(out + (size_t)tok * E_EXP * CAPV);
    v4f* cbase = (v4f*)(out + NEC + (size_t)tok * E_EXP * CAPV);
    const int NF4 = E_EXP * CAPV / 4;    // 3072
#pragma unroll
    for (int it = 0; it < NF4 / 256; ++it) {
        int f = it * 256 + tid;
        int e = f / (CAPV / 4);
        int c4 = f - e * (CAPV / 4);
        v4f dv = {0.f, 0.f, 0.f, 0.f};
        v4f cv = {0.f, 0.f, 0.f, 0.f};
        if (c4 == 0) {
            if (e == i1) { dv[0] = 1.f; cv[0] = w1; }
            else if (e == i2) { dv[0] = 1.f; cv[0] = w2; }
        }
        __builtin_nontemporal_store(dv, dbase + f);
        __builtin_nontemporal_store(cv, cbase + f);
    }
    if (tid < 2) {
        float4 pv = tid == 0 ? make_float4(p[0], p[1], p[2], p[3])
                             : make_float4(p[4], p[5], p[6], p[7]);
        ((float4*)(out + 2 * NEC + (size_t)tok * 8))[tid] = pv;
    }
}

// ---------------------------------------------------------------- aux loss
__global__ void aux_k(const float* __restrict__ probs, float* __restrict__ out_aux) {
    __shared__ float part[256];
    int tid = threadIdx.x;
    int e = tid & 7, chunk = tid >> 3;
    float s = 0.f;
    for (int t = chunk * 128; t < (chunk + 1) * 128; ++t)
        s += probs[(size_t)t * 8 + e];
    part[tid] = s;
    __syncthreads();
    if (tid < 8) {
        float tot = 0.f;
        for (int c = 0; c < 32; ++c) tot += part[c * 8 + e];
        part[tid] = tot / (float)N_TOK;
    }
    __syncthreads();
    if (tid == 0) {
        float aux = 0.f;
        for (int e2 = 0; e2 < 8; ++e2) {
            float pm = part[e2];
            aux += pm * logf(pm * 8.f + 1e-9f);
        }
        *out_aux = aux;
    }
}

// ---------------------------------------------------------------- launch
extern "C" void kernel_launch(void* const* d_in, const int* in_sizes, int n_in,
                              void* d_out, int out_size, void* d_ws, size_t ws_size,
                              hipStream_t stream) {
    const float* hid = (const float*)d_in[0];
    const float* pos = (const float*)d_in[1];
    const float* We1 = (const float*)d_in[2];
    const float* be1 = (const float*)d_in[3];
    const float* We2 = (const float*)d_in[4];
    const float* be2 = (const float*)d_in[5];
    const float* Ws1 = (const float*)d_in[6];
    const float* bs1 = (const float*)d_in[7];
    const float* Ws2 = (const float*)d_in[8];
    const float* bs2 = (const float*)d_in[9];
    const float* Wq  = (const float*)d_in[10]; const float* bq = (const float*)d_in[11];
    const float* Wk  = (const float*)d_in[12]; const float* bk = (const float*)d_in[13];
    const float* Wv  = (const float*)d_in[14]; const float* bv = (const float*)d_in[15];
    const float* Wo  = (const float*)d_in[16]; const float* bo = (const float*)d_in[17];
    const float* Wr1 = (const float*)d_in[18]; const float* br1 = (const float*)d_in[19];
    const float* Wr2 = (const float*)d_in[20]; const float* br2 = (const float*)d_in[21];

    float* out = (float*)d_out;
    char* base = (char*)d_ws;
    const size_t AC  = (size_t)N_TOK * H_DIM;
    const size_t SPC = AC * 2;
    const size_t FB  = AC * 4;
    unsigned short* B1hi = (unsigned short*)(base);
    unsigned short* B1lo = (unsigned short*)(base + SPC);
    unsigned short* B2hi = (unsigned short*)(base + FB);
    unsigned short* B2lo = (unsigned short*)(base + FB + SPC);
    unsigned short* Qhi  = (unsigned short*)(base + 2 * FB);
    unsigned short* Qlo  = (unsigned short*)(base + 2 * FB + SPC);
    unsigned short* Khi  = (unsigned short*)(base + 3 * FB);
    unsigned short* Klo  = (unsigned short*)(base + 3 * FB + SPC);
    unsigned short* VThi = (unsigned short*)(base + 4 * FB);
    unsigned short* VTlo = (unsigned short*)(base + 4 * FB + SPC);
    unsigned short* Whi  = (unsigned short*)(base + 5 * FB);
    unsigned short* Wlo  = (unsigned short*)(base + 5 * FB + (size_t)1024 * 1024 * 2);
    float* h1f     = (float*)(base + 3 * FB);
    float* seas24  = (float*)(base + 5 * FB + (size_t)1024 * 1024 * 4);
    float* seasons = seas24 + 6144;
    float* logits  = seasons + 2048;

    const size_t NEC = (size_t)N_TOK * E_EXP * CAPV;
    const float QSCALE = 0.08838834764831845f;

    season_k<<<8, 256, 0, stream>>>(seasons);
    seas24_k<<<24, 256, 0, stream>>>(seasons, Ws1, bs1, Ws2, bs2, seas24);
    convert_split_k<<<4096, 256, 0, stream>>>(hid, B1hi, B1lo, (int)(AC / 4));

    dim3 gg(16, 32), blk(256);
    dim3 wg(16, 16);

    wconv_t_k<<<wg, blk, 0, stream>>>(We1, Whi, Wlo);
    gemm_split<1, 0, 1, 0><<<gg, blk, 0, stream>>>(B1hi, B1lo, Whi, Wlo, be1,
        nullptr, B2hi, B2lo,
        We1 + (size_t)1024 * 1024, We1 + (size_t)1025 * 1024, seasons, nullptr, nullptr, 1.f);
    wconv_t_k<<<wg, blk, 0, stream>>>(We2, Whi, Wlo);
    gemm_split<2, 0, 1, 0><<<gg, blk, 0, stream>>>(B2hi, B2lo, Whi, Wlo, be2,
        nullptr, B1hi, B1lo, nullptr, nullptr, nullptr, pos, seas24, 1.f);
    wconv_t_k<<<wg, blk, 0, stream>>>(Wq, Whi, Wlo);
    gemm_split<0, 0, 1, 0><<<gg, blk, 0, stream>>>(B1hi, B1lo, Whi, Wlo, bq,
        nullptr, Qhi, Qlo, nullptr, nullptr, nullptr, nullptr, nullptr, QSCALE);
    wconv_t_k<<<wg, blk, 0, stream>>>(Wk, Whi, Wlo);
    gemm_split<0, 0, 1, 0><<<gg, blk, 0, stream>>>(B1hi, B1lo, Whi, Wlo, bk,
        nullptr, Khi, Klo, nullptr, nullptr, nullptr, nullptr, nullptr, 1.f);
    wconv_t_k<<<wg, blk, 0, stream>>>(Wv, Whi, Wlo);
    gemm_split<0, 0, 0, 1><<<gg, blk, 0, stream>>>(B1hi, B1lo, Whi, Wlo, bv,
        nullptr, VThi, VTlo, nullptr, nullptr, nullptr, nullptr, nullptr, 1.f);

    attn_mfma_k<<<dim3(32, 16), 256, 0, stream>>>(Qhi, Qlo, Khi, Klo, VThi, VTlo,
                                                  B2hi, B2lo);

    wconv_t_k<<<wg, blk, 0, stream>>>(Wo, Whi, Wlo);
    gemm_split<0, 0, 1, 0><<<gg, blk, 0, stream>>>(B2hi, B2lo, Whi, Wlo, bo,
        nullptr, B1hi, B1lo, nullptr, nullptr, nullptr, nullptr, nullptr, 1.f);
    wconv_t_k<<<wg, blk, 0, stream>>>(Wr1, Whi, Wlo);
    gemm_split<3, 1, 0, 0><<<gg, blk, 0, stream>>>(B1hi, B1lo, Whi, Wlo, br1,
        h1f, nullptr, nullptr, nullptr, nullptr, nullptr, nullptr, nullptr, 1.f);

    logits_k<<<128, 256, 0, stream>>>(h1f, Wr2, br2, logits);
    topk_fill_k<<<4096, 256, 0, stream>>>(logits, out);
    aux_k<<<1, 256, 0, stream>>>(out + 2 * NEC, out + 2 * NEC + (size_t)N_TOK * E_EXP);
}

// Round 7
// 626.826 us; speedup vs baseline: 3.6246x; 1.0034x over previous
//
#include <hip/hip_runtime.h>
#include <hip/hip_fp16.h>
#include <math.h>

#define N_TOK 4096
#define S_LEN 2048
#define H_DIM 1024
#define E_EXP 8
#define CAPV  1536
#define NHEAD 8
#define HDHD  128

typedef __attribute__((ext_vector_type(8))) _Float16 v8h;
typedef __attribute__((ext_vector_type(4))) float v4f;

__device__ __forceinline__ void splitf16(float v, unsigned short& h, unsigned short& l) {
    __half hh = __float2half(v);
    h = __half_as_ushort(hh);
    l = __half_as_ushort(__float2half(v - __half2float(hh)));
}

__device__ __forceinline__ void gld_lds16(const void* g, void* l) {
    __builtin_amdgcn_global_load_lds(
        (const __attribute__((address_space(1))) unsigned int*)g,
        (__attribute__((address_space(3))) unsigned int*)l,
        16, 0, 0);
}

// ---------------------------------------------------------------- seasons
__global__ void season_k(float* seasons) {
    int s = blockIdx.x * 256 + threadIdx.x;
    if (s < S_LEN) {
        double a = (double)s * 2.0 * M_PI / 24.0;
        seasons[s] = (float)sin(a);
    }
}

__global__ void seas24_k(const float* __restrict__ seasons,
                         const float* __restrict__ Ws1, const float* __restrict__ bs1,
                         const float* __restrict__ Ws2, const float* __restrict__ bs2,
                         float* __restrict__ seas24) {
    __shared__ float hbuf[256];
    int m = blockIdx.x;
    float sv = seasons[m];
    int j = threadIdx.x;
    hbuf[j] = fmaxf(sv * Ws1[j] + bs1[j], 0.f);
    __syncthreads();
    float acc = bs2[j];
    for (int i = 0; i < 256; ++i) acc = fmaf(hbuf[i], Ws2[i * 256 + j], acc);
    seas24[m * 256 + j] = acc;
}

// ---------------------------------------------------------------- Wr2 transpose (8x1024)
__global__ void wr2t_k(const float* __restrict__ Wr2, float* __restrict__ Wr2T) {
    int i = blockIdx.x * 256 + threadIdx.x;   // 8192
    int k = i >> 3, e = i & 7;
    Wr2T[e * 1024 + k] = Wr2[i];
}

// ---------------------------------------------------------------- f32 -> f16 hi/lo split
__global__ void convert_split_k(const float* __restrict__ in,
                                unsigned short* __restrict__ hi,
                                unsigned short* __restrict__ lo, int n4) {
    int i = blockIdx.x * 256 + threadIdx.x;
    if (i >= n4) return;
    float4 v = ((const float4*)in)[i];
    ushort4 h, l;
    splitf16(v.x, h.x, l.x);
    splitf16(v.y, h.y, l.y);
    splitf16(v.z, h.z, l.z);
    splitf16(v.w, h.w, l.w);
    ((ushort4*)hi)[i] = h;
    ((ushort4*)lo)[i] = l;
}

// ---------------------------------------------------------------- W[1024][1024] -> W^T hi/lo f16
__device__ __forceinline__ void wconv_body(const float* __restrict__ W,
                                           unsigned short* __restrict__ Thi,
                                           unsigned short* __restrict__ Tlo) {
    __shared__ unsigned short Hs[64][65];
    __shared__ unsigned short Ls[64][65];
    int k0 = blockIdx.y * 64, n0 = blockIdx.x * 64;
    int tid = threadIdx.x;
#pragma unroll
    for (int i = 0; i < 4; ++i) {
        int idx = tid + i * 256;
        int kk = idx >> 4, n4 = idx & 15;
        float4 v = *(const float4*)(W + (size_t)(k0 + kk) * 1024 + n0 + n4 * 4);
        unsigned short h, l;
        splitf16(v.x, h, l); Hs[n4 * 4 + 0][kk] = h; Ls[n4 * 4 + 0][kk] = l;
        splitf16(v.y, h, l); Hs[n4 * 4 + 1][kk] = h; Ls[n4 * 4 + 1][kk] = l;
        splitf16(v.z, h, l); Hs[n4 * 4 + 2][kk] = h; Ls[n4 * 4 + 2][kk] = l;
        splitf16(v.w, h, l); Hs[n4 * 4 + 3][kk] = h; Ls[n4 * 4 + 3][kk] = l;
    }
    __syncthreads();
#pragma unroll
    for (int i = 0; i < 4; ++i) {
        int idx = tid + i * 256;
        int n = idx >> 4, k4 = idx & 15;
        ushort4 h = make_ushort4(Hs[n][k4 * 4], Hs[n][k4 * 4 + 1], Hs[n][k4 * 4 + 2], Hs[n][k4 * 4 + 3]);
        ushort4 l = make_ushort4(Ls[n][k4 * 4], Ls[n][k4 * 4 + 1], Ls[n][k4 * 4 + 2], Ls[n][k4 * 4 + 3]);
        *(ushort4*)(Thi + (size_t)(n0 + n) * 1024 + k0 + k4 * 4) = h;
        *(ushort4*)(Tlo + (size_t)(n0 + n) * 1024 + k0 + k4 * 4) = l;
    }
}

__global__ __launch_bounds__(256) void wconv_t_k(const float* __restrict__ W,
                                                 unsigned short* __restrict__ Thi,
                                                 unsigned short* __restrict__ Tlo) {
    wconv_body(W, Thi, Tlo);
}

struct WBatch {
    const float* src[7];
    unsigned short* dh[7];
    unsigned short* dl[7];
};

__global__ __launch_bounds__(256) void wconv_batch_k(WBatch wb) {
    int i = blockIdx.z;
    wconv_body(wb.src[i], wb.dh[i], wb.dl[i]);
}

// ---------------------------------------------------------------- split-f16 MFMA GEMM
// double-buffered 2-phase: stage(next) -> compute(cur) -> one __syncthreads.
template <int MODE, int EMITF, int EMITS, int EMITT>
__global__ __launch_bounds__(256, 2) void gemm_split(
    const unsigned short* __restrict__ Ahi, const unsigned short* __restrict__ Alo,
    const unsigned short* __restrict__ WThi, const unsigned short* __restrict__ WTlo,
    const float* __restrict__ bias, float* __restrict__ Cf,
    unsigned short* __restrict__ Chi, unsigned short* __restrict__ Clo,
    const float* __restrict__ rowT, const float* __restrict__ rowS,
    const float* __restrict__ seasons, const float* __restrict__ pos,
    const float* __restrict__ seas24, float escale) {
    __shared__ unsigned short Ash[2][128 * 32];
    __shared__ unsigned short Asl[2][128 * 32];
    __shared__ unsigned short Bsh[2][64 * 32];
    __shared__ unsigned short Bsl[2][64 * 32];
    int tid = threadIdx.x;
    int lane = tid & 63, w = tid >> 6;
    int l15 = lane & 15, l16 = lane >> 4;
    int wm = (w >> 1) * 64, wn = (w & 1) * 32;
    int m0 = blockIdx.y * 128, n0 = blockIdx.x * 64;

    int ac0 = w * 128 + lane;
    int ac1 = ac0 + 64;
    int bc  = w * 64 + lane;
    int ar0 = ac0 >> 2, ar1 = ac1 >> 2, bn = bc >> 2;
    size_t a_src0 = (size_t)(m0 + ar0) * 1024 + (((ac0 & 3) ^ (ar0 & 3)) * 8);
    size_t a_src1 = (size_t)(m0 + ar1) * 1024 + (((ac1 & 3) ^ (ar1 & 3)) * 8);
    size_t b_src  = (size_t)(n0 + bn) * 1024 + (((bc & 3) ^ (bn & 3)) * 8);

    int a_off[4], b_off[2];
#pragma unroll
    for (int mi = 0; mi < 4; ++mi) {
        int row = wm + mi * 16 + l15;
        a_off[mi] = row * 32 + ((l16 ^ (row & 3)) * 8);
    }
#pragma unroll
    for (int ni = 0; ni < 2; ++ni) {
        int n = wn + ni * 16 + l15;
        b_off[ni] = n * 32 + ((l16 ^ (n & 3)) * 8);
    }

    auto STAGE = [&](int buf, int k0) {
        gld_lds16(Ahi + a_src0 + k0, &Ash[buf][ac0 * 8]);
        gld_lds16(Ahi + a_src1 + k0, &Ash[buf][ac1 * 8]);
        gld_lds16(Alo + a_src0 + k0, &Asl[buf][ac0 * 8]);
        gld_lds16(Alo + a_src1 + k0, &Asl[buf][ac1 * 8]);
        gld_lds16(WThi + b_src + k0, &Bsh[buf][bc * 8]);
        gld_lds16(WTlo + b_src + k0, &Bsl[buf][bc * 8]);
    };

    v4f acc[4][2] = {};
    STAGE(0, 0);
    __syncthreads();

    for (int kk = 0; kk < 32; ++kk) {
        int cur = kk & 1;
        if (kk < 31) STAGE(cur ^ 1, (kk + 1) * 32);
        v8h ah[4], al[4], bh[2], bl[2];
#pragma unroll
        for (int mi = 0; mi < 4; ++mi) {
            ah[mi] = *(const v8h*)&Ash[cur][a_off[mi]];
            al[mi] = *(const v8h*)&Asl[cur][a_off[mi]];
        }
#pragma unroll
        for (int ni = 0; ni < 2; ++ni) {
            bh[ni] = *(const v8h*)&Bsh[cur][b_off[ni]];
            bl[ni] = *(const v8h*)&Bsl[cur][b_off[ni]];
        }
#pragma unroll
        for (int mi = 0; mi < 4; ++mi)
#pragma unroll
            for (int ni = 0; ni < 2; ++ni) {
                acc[mi][ni] = __builtin_amdgcn_mfma_f32_16x16x32_f16(ah[mi], bh[ni], acc[mi][ni], 0, 0, 0);
                acc[mi][ni] = __builtin_amdgcn_mfma_f32_16x16x32_f16(al[mi], bh[ni], acc[mi][ni], 0, 0, 0);
                acc[mi][ni] = __builtin_amdgcn_mfma_f32_16x16x32_f16(ah[mi], bl[ni], acc[mi][ni], 0, 0, 0);
            }
        __syncthreads();
    }

    if (EMITT) {
#pragma unroll
        for (int mi = 0; mi < 4; ++mi) {
            int row0 = m0 + wm + mi * 16 + l16 * 4;
            int bb = row0 >> 11, ss = row0 & 2047;
#pragma unroll
            for (int ni = 0; ni < 2; ++ni) {
                int col = n0 + wn + ni * 16 + l15;
                int hh = col >> 7, dd = col & 127;
                size_t base = ((size_t)((bb * 8 + hh) * 128 + dd)) * 2048 + ss;
                ushort4 vh, vl;
                float v0 = acc[mi][ni][0] + bias[col];
                float v1 = acc[mi][ni][1] + bias[col];
                float v2 = acc[mi][ni][2] + bias[col];
                float v3 = acc[mi][ni][3] + bias[col];
                splitf16(v0, vh.x, vl.x);
                splitf16(v1, vh.y, vl.y);
                splitf16(v2, vh.z, vl.z);
                splitf16(v3, vh.w, vl.w);
                *(ushort4*)(Chi + base) = vh;
                *(ushort4*)(Clo + base) = vl;
            }
        }
    } else {
#pragma unroll
        for (int mi = 0; mi < 4; ++mi) {
#pragma unroll
            for (int r = 0; r < 4; ++r) {
                int row = m0 + wm + mi * 16 + l16 * 4 + r;
                int s = row & (S_LEN - 1);
                float tval = 0.f, seval = 0.f;
                if (MODE == 1) { tval = (float)s; seval = seasons[s]; }
#pragma unroll
                for (int ni = 0; ni < 2; ++ni) {
                    int col = n0 + wn + ni * 16 + l15;
                    float v = acc[mi][ni][r] + bias[col];
                    if (MODE == 1) v += tval * rowT[col] + seval * rowS[col];
                    if (MODE == 2) v += pos[(size_t)s * 1024 + col] + seas24[(s % 24) * 256 + (col & 255)];
                    if (MODE == 1 || MODE == 3) v = fmaxf(v, 0.f);
                    size_t o = (size_t)row * 1024 + col;
                    if (EMITF) Cf[o] = v;
                    if (EMITS) {
                        unsigned short hu, lu;
                        splitf16(v * escale, hu, lu);
                        Chi[o] = hu; Clo[o] = lu;
                    }
                }
            }
        }
    }
}

// ---------------------------------------------------------------- MFMA attention (double-buffered, 1 barrier/iter)
// Ps rows are per-wave-exclusive (write rows wm+l16*4+r, read rows wm+l15,
// both in [wm,wm+16)) -> no cross-wave barrier needed between P-write and PV.
#define ATTN_LDS_BYTES (4 * 2 * 4096 * 2 + 64 * 32 * 4)   // 73728

__global__ __launch_bounds__(256, 2) void attn_mfma_k(
    const unsigned short* __restrict__ qhi, const unsigned short* __restrict__ qlo,
    const unsigned short* __restrict__ khi, const unsigned short* __restrict__ klo,
    const unsigned short* __restrict__ vthi, const unsigned short* __restrict__ vtlo,
    unsigned short* __restrict__ ctx_hi, unsigned short* __restrict__ ctx_lo) {
    extern __shared__ char smem_raw[];
    unsigned short* Ks_hi = (unsigned short*)smem_raw;     // [2][4096]
    unsigned short* Ks_lo = Ks_hi + 2 * 4096;
    unsigned short* Vs_hi = Ks_lo + 2 * 4096;
    unsigned short* Vs_lo = Vs_hi + 2 * 4096;
    unsigned int*   Ps    = (unsigned int*)(Vs_lo + 2 * 4096);   // [64*32]

    int bh = blockIdx.y;
    int b = bh >> 3, h = bh & 7;
    int q0 = blockIdx.x * 64;
    int tid = threadIdx.x;
    int lane = tid & 63, w = tid >> 6;
    int l15 = lane & 15, l16 = lane >> 4;
    int wm = w * 16;

    v8h qa_h[4], qa_l[4];
    {
        size_t qrow = (size_t)(b * S_LEN + q0 + wm + l15) * H_DIM + h * HDHD;
#pragma unroll
        for (int ks = 0; ks < 4; ++ks) {
            qa_h[ks] = *(const v8h*)(qhi + qrow + ks * 32 + l16 * 8);
            qa_l[ks] = *(const v8h*)(qlo + qrow + ks * 32 + l16 * 8);
        }
    }

    int ktok1 = tid >> 4, kslot1 = tid & 15;
    int ktok2 = ktok1 + 16;
    size_t ksrc1 = (size_t)(b * S_LEN + ktok1) * H_DIM + h * HDHD + ((kslot1 ^ (ktok1 & 7)) * 8);
    size_t ksrc2 = (size_t)(b * S_LEN + ktok2) * H_DIM + h * HDHD + ((kslot1 ^ (ktok2 & 7)) * 8);
    int vd1 = tid >> 2, vslot1 = tid & 3;
    int vd2 = vd1 + 64;
    size_t vsrc1 = (size_t)(bh * HDHD + vd1) * S_LEN + ((vslot1 ^ ((vd1 >> 1) & 3)) * 8);
    size_t vsrc2 = (size_t)(bh * HDHD + vd2) * S_LEN + ((vslot1 ^ ((vd2 >> 1) & 3)) * 8);

    auto STAGE = [&](int buf, int kt) {
        size_t koff = (size_t)kt * H_DIM;
        int o = buf * 4096;
        gld_lds16(khi + ksrc1 + koff, &Ks_hi[o + tid * 8]);
        gld_lds16(khi + ksrc2 + koff, &Ks_hi[o + (tid + 256) * 8]);
        gld_lds16(klo + ksrc1 + koff, &Ks_lo[o + tid * 8]);
        gld_lds16(klo + ksrc2 + koff, &Ks_lo[o + (tid + 256) * 8]);
        gld_lds16(vthi + vsrc1 + kt, &Vs_hi[o + tid * 8]);
        gld_lds16(vthi + vsrc2 + kt, &Vs_hi[o + (tid + 256) * 8]);
        gld_lds16(vtlo + vsrc1 + kt, &Vs_lo[o + tid * 8]);
        gld_lds16(vtlo + vsrc2 + kt, &Vs_lo[o + (tid + 256) * 8]);
    };

    v4f accO[8] = {};
    float mreg[4] = {-1e30f, -1e30f, -1e30f, -1e30f};
    float lreg[4] = {};

    STAGE(0, 0);
    __syncthreads();

    for (int it = 0; it < 64; ++it) {
        int cur = it & 1;
        int co = cur * 4096;
        if (it < 63) STAGE(cur ^ 1, (it + 1) * 32);

        // ---- QK^T: S[16 q][32 tok]
        v4f s0 = {}, s1 = {};
#pragma unroll
        for (int ks = 0; ks < 4; ++ks) {
#pragma unroll
            for (int nt = 0; nt < 2; ++nt) {
                int tok = nt * 16 + l15;
                int slot = (ks * 4 + l16) ^ (tok & 7);
                v8h bhf = *(const v8h*)&Ks_hi[co + tok * 128 + slot * 8];
                v8h blf = *(const v8h*)&Ks_lo[co + tok * 128 + slot * 8];
                v4f& ss = nt ? s1 : s0;
                ss = __builtin_amdgcn_mfma_f32_16x16x32_f16(qa_h[ks], bhf, ss, 0, 0, 0);
                ss = __builtin_amdgcn_mfma_f32_16x16x32_f16(qa_l[ks], bhf, ss, 0, 0, 0);
                ss = __builtin_amdgcn_mfma_f32_16x16x32_f16(qa_h[ks], blf, ss, 0, 0, 0);
            }
        }

        // ---- online softmax
        float p0[4], p1[4], alpha[4];
#pragma unroll
        for (int r = 0; r < 4; ++r) {
            float tmax = fmaxf(s0[r], s1[r]);
            tmax = fmaxf(tmax, __shfl_xor(tmax, 1));
            tmax = fmaxf(tmax, __shfl_xor(tmax, 2));
            tmax = fmaxf(tmax, __shfl_xor(tmax, 4));
            tmax = fmaxf(tmax, __shfl_xor(tmax, 8));
            float mnew = fmaxf(mreg[r], tmax);
            alpha[r] = __expf(mreg[r] - mnew);
            p0[r] = __expf(s0[r] - mnew);
            p1[r] = __expf(s1[r] - mnew);
            float lt = p0[r] + p1[r];
            lt += __shfl_xor(lt, 1);
            lt += __shfl_xor(lt, 2);
            lt += __shfl_xor(lt, 4);
            lt += __shfl_xor(lt, 8);
            lreg[r] = lreg[r] * alpha[r] + lt;
            mreg[r] = mnew;
        }
#pragma unroll
        for (int nt = 0; nt < 8; ++nt)
#pragma unroll
            for (int r = 0; r < 4; ++r) accO[nt][r] *= alpha[r];

        // ---- P -> Ps (same-wave rows only; no barrier needed)
#pragma unroll
        for (int r = 0; r < 4; ++r) {
            int qq = wm + l16 * 4 + r;
            unsigned short ph, pl;
            splitf16(p0[r], ph, pl);
            int k0i = l15;
            Ps[qq * 32 + ((((k0i >> 2) ^ (qq & 7)) << 2) | (k0i & 3))] =
                (unsigned)ph | ((unsigned)pl << 16);
            splitf16(p1[r], ph, pl);
            int k1i = 16 + l15;
            Ps[qq * 32 + ((((k1i >> 2) ^ (qq & 7)) << 2) | (k1i & 3))] =
                (unsigned)ph | ((unsigned)pl << 16);
        }

        // ---- PV
        int qq = wm + l15;
        int sA = (l16 * 2) ^ (qq & 7);
        int sB = (l16 * 2 + 1) ^ (qq & 7);
        uint4 ua = *(const uint4*)&Ps[qq * 32 + sA * 4];
        uint4 ub = *(const uint4*)&Ps[qq * 32 + sB * 4];
        uint4 ahw, alw;
        ahw.x = (ua.x & 0xffffu) | (ua.y << 16);
        ahw.y = (ua.z & 0xffffu) | (ua.w << 16);
        ahw.z = (ub.x & 0xffffu) | (ub.y << 16);
        ahw.w = (ub.z & 0xffffu) | (ub.w << 16);
        alw.x = (ua.x >> 16) | (ua.y & 0xffff0000u);
        alw.y = (ua.z >> 16) | (ua.w & 0xffff0000u);
        alw.z = (ub.x >> 16) | (ub.y & 0xffff0000u);
        alw.w = (ub.z >> 16) | (ub.w & 0xffff0000u);
        v8h pA_h = __builtin_bit_cast(v8h, ahw);
        v8h pA_l = __builtin_bit_cast(v8h, alw);
#pragma unroll
        for (int nt = 0; nt < 8; ++nt) {
            int d = nt * 16 + l15;
            int slot = l16 ^ ((d >> 1) & 3);
            v8h vhf = *(const v8h*)&Vs_hi[co + d * 32 + slot * 8];
            v8h vlf = *(const v8h*)&Vs_lo[co + d * 32 + slot * 8];
            accO[nt] = __builtin_amdgcn_mfma_f32_16x16x32_f16(pA_h, vhf, accO[nt], 0, 0, 0);
            accO[nt] = __builtin_amdgcn_mfma_f32_16x16x32_f16(pA_l, vhf, accO[nt], 0, 0, 0);
            accO[nt] = __builtin_amdgcn_mfma_f32_16x16x32_f16(pA_h, vlf, accO[nt], 0, 0, 0);
        }
        __syncthreads();   // drains next-tile staging; cur reads + Ps reads done
    }

    float linv[4];
#pragma unroll
    for (int r = 0; r < 4; ++r) linv[r] = 1.f / lreg[r];
#pragma unroll
    for (int nt = 0; nt < 8; ++nt) {
#pragma unroll
        for (int r = 0; r < 4; ++r) {
            size_t o = (size_t)(b * S_LEN + q0 + wm + l16 * 4 + r) * H_DIM + h * HDHD + nt * 16 + l15;
            unsigned short hu, lu;
            splitf16(accO[nt][r] * linv[r], hu, lu);
            ctx_hi[o] = hu;
            ctx_lo[o] = lu;
        }
    }
}

// ---------------------------------------------------------------- router logits (vectorized)
// block: 8 tokens; thread = tok(8) x e(8) x chunk(4)
__global__ __launch_bounds__(256) void logits_k(const float* __restrict__ h1,
                                                const float* __restrict__ Wr2T,
                                                const float* __restrict__ br2,
                                                float* __restrict__ logits) {
    __shared__ float part[256];
    int tid = threadIdx.x;
    int tok8 = tid >> 5;
    int e = (tid >> 2) & 7;
    int ch = tid & 3;
    int tok = blockIdx.x * 8 + tok8;
    const float4* h4 = (const float4*)(h1 + (size_t)tok * 1024 + ch * 256);
    const float4* w4 = (const float4*)(Wr2T + (size_t)e * 1024 + ch * 256);
    float acc = 0.f;
#pragma unroll
    for (int i = 0; i < 64; ++i) {
        float4 a = h4[i];
        float4 bb = w4[i];
        acc = fmaf(a.x, bb.x, fmaf(a.y, bb.y, fmaf(a.z, bb.z, fmaf(a.w, bb.w, acc))));
    }
    part[tid] = acc;
    __syncthreads();
    if (ch == 0) {
        float s = part[tid] + part[tid + 1] + part[tid + 2] + part[tid + 3] + br2[e];
        logits[(size_t)tok * 8 + e] = s;
    }
}

// ---------------------------------------------------------------- fused softmax+top2+zero-fill writer
__global__ __launch_bounds__(256) void topk_fill_k(const float* __restrict__ logits,
                                                   float* __restrict__ out) {
    int tok = blockIdx.x;
    int tid = threadIdx.x;
    float l[8], p[8];
    float mx = -1e30f;
#pragma unroll
    for (int e = 0; e < 8; ++e) { l[e] = logits[(size_t)tok * 8 + e]; mx = fmaxf(mx, l[e]); }
    float sum = 0.f;
#pragma unroll
    for (int e = 0; e < 8; ++e) { p[e] = __expf(l[e] - mx); sum += p[e]; }
    float inv = 1.f / sum;
#pragma unroll
    for (int e = 0; e < 8; ++e) p[e] *= inv;
    int i1 = 0;
#pragma unroll
    for (int e = 1; e < 8; ++e) if (p[e] > p[i1]) i1 = e;
    int i2 = -1;
#pragma unroll
    for (int e = 0; e < 8; ++e) {
        if (e == i1) continue;
        if (i2 < 0 || p[e] > p[i2]) i2 = e;
    }
    float tv = p[i1] + p[i2];
    float w1 = p[i1] / tv, w2 = p[i2] / tv;

    const size_t NEC = (size_t)N_TOK * E_EXP * CAPV;
    v4f* dbase = (v4f*)(out + (size_t)tok * E_EXP * CAPV);
    v4f* cbase = (v4f*)(out + NEC + (size_t)tok * E_EXP * CAPV);
    const int NF4 = E_EXP * CAPV / 4;
#pragma unroll
    for (int it = 0; it < NF4 / 256; ++it) {
        int f = it * 256 + tid;
        int e = f / (CAPV / 4);
        int c4 = f - e * (CAPV / 4);
        v4f dv = {0.f, 0.f, 0.f, 0.f};
        v4f cv = {0.f, 0.f, 0.f, 0.f};
        if (c4 == 0) {
            if (e == i1) { dv[0] = 1.f; cv[0] = w1; }
            else if (e == i2) { dv[0] = 1.f; cv[0] = w2; }
        }
        __builtin_nontemporal_store(dv, dbase + f);
        __builtin_nontemporal_store(cv, cbase + f);
    }
    if (tid < 2) {
        float4 pv = tid == 0 ? make_float4(p[0], p[1], p[2], p[3])
                             : make_float4(p[4], p[5], p[6], p[7]);
        ((float4*)(out + 2 * NEC + (size_t)tok * 8))[tid] = pv;
    }
}

// ---------------------------------------------------------------- aux loss
__global__ void aux_k(const float* __restrict__ probs, float* __restrict__ out_aux) {
    __shared__ float part[256];
    int tid = threadIdx.x;
    int e = tid & 7, chunk = tid >> 3;
    float s = 0.f;
    for (int t = chunk * 128; t < (chunk + 1) * 128; ++t)
        s += probs[(size_t)t * 8 + e];
    part[tid] = s;
    __syncthreads();
    if (tid < 8) {
        float tot = 0.f;
        for (int c = 0; c < 32; ++c) tot += part[c * 8 + e];
        part[tid] = tot / (float)N_TOK;
    }
    __syncthreads();
    if (tid == 0) {
        float aux = 0.f;
        for (int e2 = 0; e2 < 8; ++e2) {
            float pm = part[e2];
            aux += pm * logf(pm * 8.f + 1e-9f);
        }
        *out_aux = aux;
    }
}

// ---------------------------------------------------------------- launch
extern "C" void kernel_launch(void* const* d_in, const int* in_sizes, int n_in,
                              void* d_out, int out_size, void* d_ws, size_t ws_size,
                              hipStream_t stream) {
    const float* hid = (const float*)d_in[0];
    const float* pos = (const float*)d_in[1];
    const float* We1 = (const float*)d_in[2];
    const float* be1 = (const float*)d_in[3];
    const float* We2 = (const float*)d_in[4];
    const float* be2 = (const float*)d_in[5];
    const float* Ws1 = (const float*)d_in[6];
    const float* bs1 = (const float*)d_in[7];
    const float* Ws2 = (const float*)d_in[8];
    const float* bs2 = (const float*)d_in[9];
    const float* Wq  = (const float*)d_in[10]; const float* bq = (const float*)d_in[11];
    const float* Wk  = (const float*)d_in[12]; const float* bk = (const float*)d_in[13];
    const float* Wv  = (const float*)d_in[14]; const float* bv = (const float*)d_in[15];
    const float* Wo  = (const float*)d_in[16]; const float* bo = (const float*)d_in[17];
    const float* Wr1 = (const float*)d_in[18]; const float* br1 = (const float*)d_in[19];
    const float* Wr2 = (const float*)d_in[20]; const float* br2 = (const float*)d_in[21];

    float* out = (float*)d_out;
    char* base = (char*)d_ws;
    const size_t AC  = (size_t)N_TOK * H_DIM;
    const size_t SPC = AC * 2;
    const size_t FB  = AC * 4;
    const size_t WSZ = (size_t)1024 * 1024 * 4;   // one weight pair (hi 2MB + lo 2MB)

    unsigned short* B1hi = (unsigned short*)(base);
    unsigned short* B1lo = (unsigned short*)(base + SPC);
    unsigned short* B2hi = (unsigned short*)(base + FB);
    unsigned short* B2lo = (unsigned short*)(base + FB + SPC);
    unsigned short* Qhi  = (unsigned short*)(base + 2 * FB);
    unsigned short* Qlo  = (unsigned short*)(base + 2 * FB + SPC);
    unsigned short* Khi  = (unsigned short*)(base + 3 * FB);
    unsigned short* Klo  = (unsigned short*)(base + 3 * FB + SPC);
    unsigned short* VThi = (unsigned short*)(base + 4 * FB);
    unsigned short* VTlo = (unsigned short*)(base + 4 * FB + SPC);
    float* h1f = (float*)(base + 3 * FB);   // reuses K region (free after attn)

    char* wbase = base + 5 * FB;
    bool batched = ws_size >= 5 * FB + 7 * WSZ + (1u << 20);
    unsigned short* Whi[7];
    unsigned short* Wlo[7];
    for (int i = 0; i < 7; ++i) {
        size_t off = batched ? (size_t)i * WSZ : 0;
        Whi[i] = (unsigned short*)(wbase + off);
        Wlo[i] = (unsigned short*)(wbase + off + WSZ / 2);
    }
    char* smalls = wbase + (batched ? 7 * WSZ : WSZ);
    float* wr2t    = (float*)smalls;            // 8192
    float* seas24  = wr2t + 8192;               // 6144
    float* seasons = seas24 + 6144;             // 2048
    float* logits  = seasons + 2048;            // 32768

    const size_t NEC = (size_t)N_TOK * E_EXP * CAPV;
    const float QSCALE = 0.08838834764831845f;

    static bool attr_set = false;
    if (!attr_set) {
        hipFuncSetAttribute((const void*)attn_mfma_k,
                            hipFuncAttributeMaxDynamicSharedMemorySize,
                            ATTN_LDS_BYTES);
        attr_set = true;
    }

    dim3 gg(16, 32), blk(256);
    dim3 wg(16, 16);

    season_k<<<8, 256, 0, stream>>>(seasons);
    seas24_k<<<24, 256, 0, stream>>>(seasons, Ws1, bs1, Ws2, bs2, seas24);
    wr2t_k<<<32, 256, 0, stream>>>(Wr2, wr2t);
    convert_split_k<<<4096, 256, 0, stream>>>(hid, B1hi, B1lo, (int)(AC / 4));

    const float* wsrc[7] = {We1, We2, Wq, Wk, Wv, Wo, Wr1};
    if (batched) {
        WBatch wb;
        for (int i = 0; i < 7; ++i) { wb.src[i] = wsrc[i]; wb.dh[i] = Whi[i]; wb.dl[i] = Wlo[i]; }
        wconv_batch_k<<<dim3(16, 16, 7), blk, 0, stream>>>(wb);
    }

    auto conv = [&](int i) {
        if (!batched) wconv_t_k<<<wg, blk, 0, stream>>>(wsrc[i], Whi[i], Wlo[i]);
    };

    conv(0);
    gemm_split<1, 0, 1, 0><<<gg, blk, 0, stream>>>(B1hi, B1lo, Whi[0], Wlo[0], be1,
        nullptr, B2hi, B2lo,
        We1 + (size_t)1024 * 1024, We1 + (size_t)1025 * 1024, seasons, nullptr, nullptr, 1.f);
    conv(1);
    gemm_split<2, 0, 1, 0><<<gg, blk, 0, stream>>>(B2hi, B2lo, Whi[1], Wlo[1], be2,
        nullptr, B1hi, B1lo, nullptr, nullptr, nullptr, pos, seas24, 1.f);
    conv(2);
    gemm_split<0, 0, 1, 0><<<gg, blk, 0, stream>>>(B1hi, B1lo, Whi[2], Wlo[2], bq,
        nullptr, Qhi, Qlo, nullptr, nullptr, nullptr, nullptr, nullptr, QSCALE);
    conv(3);
    gemm_split<0, 0, 1, 0><<<gg, blk, 0, stream>>>(B1hi, B1lo, Whi[3], Wlo[3], bk,
        nullptr, Khi, Klo, nullptr, nullptr, nullptr, nullptr, nullptr, 1.f);
    conv(4);
    gemm_split<0, 0, 0, 1><<<gg, blk, 0, stream>>>(B1hi, B1lo, Whi[4], Wlo[4], bv,
        nullptr, VThi, VTlo, nullptr, nullptr, nullptr, nullptr, nullptr, 1.f);

    attn_mfma_k<<<dim3(32, 16), 256, ATTN_LDS_BYTES, stream>>>(Qhi, Qlo, Khi, Klo,
                                                               VThi, VTlo, B2hi, B2lo);

    conv(5);
    gemm_split<0, 0, 1, 0><<<gg, blk, 0, stream>>>(B2hi, B2lo, Whi[5], Wlo[5], bo,
        nullptr, B1hi, B1lo, nullptr, nullptr, nullptr, nullptr, nullptr, 1.f);
    conv(6);
    gemm_split<3, 1, 0, 0><<<gg, blk, 0, stream>>>(B1hi, B1lo, Whi[6], Wlo[6], br1,
        h1f, nullptr, nullptr, nullptr, nullptr, nullptr, nullptr, nullptr, 1.f);

    logits_k<<<512, 256, 0, stream>>>(h1f, wr2t, br2, logits);
    topk_fill_k<<<4096, 256, 0, stream>>>(logits, out);
    aux_k<<<1, 256, 0, stream>>>(out + 2 * NEC, out + 2 * NEC + (size_t)N_TOK * E_EXP);
}